// Round 1
// 390.318 us; speedup vs baseline: 1.0744x; 1.0744x over previous
//
#include <hip/hip_runtime.h>
#include <hip/hip_bf16.h>

// MoE block: N=8192, D=1024, H=1024, E=16, top-k=2. Inputs fp32, output fp32.
// out[n] = w1*(x@W_e1 + b_e1) + w2*(x@W_e2 + b_e2), w = top-2 of softmax.
//
// Round-6: router rewritten. Old router: wave-per-token, 16 scalar global
// loads of rw per lane per j (64 cache lines per instruction, latency-bound,
// 160 us). New router: lane = (d_stripe, expert): ds=lane>>4 owns a 256-wide
// D stripe, e=lane&15 owns one expert. rw loads are dense/coalesced
// (addr = ds*4096 + j*16 + e -> 4x64B transactions per instr), x is float4
// per token per 4 d's. 2 tokens per wave. Inner FMAs in fp32 (full 64-lane
// occupancy); every 32 terms the fp32 group sum drains into a double
// accumulator (logit abs err ~1e-7, below the fp32 reference's own rounding
// noise -> top-2 selection parity kept). Cross-stripe reduce = 2 double
// shuffles; serial top-2 on double logits (same tie-break as before);
// weights via expf.
//
// Expert GEMM (unchanged): bf16 MFMA 16x16x32, 128x128 tile, BK=32,
// fp32->bf16 RNE during LDS staging, KPAD=40 rows.
//   pass A (ADD=0): slot-0 lists -> out = w*(x@W+b)   (covers every token)
//   pass B (ADD=1): slot-1 lists -> out += w*(x@W+b)  (fp32 RMW, race-free)

#define N_TOK 8192
#define D_DIM 1024
#define H_DIM 1024
#define E_NUM 16
#define CAP   1024
#define KPAD  40    // LDS row stride in ushorts (80 B)

typedef __attribute__((ext_vector_type(4))) float f32x4;
typedef __attribute__((ext_vector_type(8))) short bf16x8;

__device__ __forceinline__ unsigned short f2bf(float f) {
    unsigned int u = __float_as_uint(f);
    unsigned int r = u + 0x7fffu + ((u >> 16) & 1u);   // RNE
    return (unsigned short)(r >> 16);
}
__device__ __forceinline__ unsigned int pk2bf(float lo, float hi) {
    return (unsigned int)f2bf(lo) | ((unsigned int)f2bf(hi) << 16);
}

__global__ __launch_bounds__(256) void router_kernel(
    const float* __restrict__ x,
    const float* __restrict__ rw,
    const float* __restrict__ rb,
    int* __restrict__ counts0, int* __restrict__ counts1,
    int2* __restrict__ entries0, int2* __restrict__ entries1)
{
    const int wave = threadIdx.x >> 6;
    const int lane = threadIdx.x & 63;
    const int ds   = lane >> 4;        // D stripe 0..3 (owns d in [ds*256, ds*256+256))
    const int e    = lane & 15;        // expert
    const int t0   = blockIdx.x * 8 + wave * 2;   // this wave's two tokens

    const float* x0  = x + (size_t)t0 * D_DIM + ds * 256;
    const float* x1  = x0 + D_DIM;
    const float* rwp = rw + ds * 4096 + e;        // rw[(ds*256 + j)*16 + e]

    // fp32 inner FMA, drained into double every 32 terms (8 jb-iters x 4).
    double acc0 = 0.0, acc1 = 0.0;
    for (int g = 0; g < 8; ++g) {
        float s0 = 0.0f, s1 = 0.0f;
#pragma unroll
        for (int u = 0; u < 8; ++u) {
            const int jb = g * 8 + u;                       // 4 d's per jb
            const float4 a = *(const float4*)(x0 + jb * 4); // broadcast within 16-lane grp
            const float4 b = *(const float4*)(x1 + jb * 4);
            const float w0 = rwp[jb * 64];                  // d = ds*256 + jb*4 + 0
            const float w1 = rwp[jb * 64 + 16];             // ... + 1
            const float w2 = rwp[jb * 64 + 32];             // ... + 2
            const float w3 = rwp[jb * 64 + 48];             // ... + 3
            s0 = fmaf(a.w, w3, fmaf(a.z, w2, fmaf(a.y, w1, fmaf(a.x, w0, s0))));
            s1 = fmaf(b.w, w3, fmaf(b.z, w2, fmaf(b.y, w1, fmaf(b.x, w0, s1))));
        }
        acc0 += (double)s0;
        acc1 += (double)s1;
    }

    // reduce over the 4 d-stripes (lanes e, e+16, e+32, e+48) in double
    double v0 = acc0, v1 = acc1;
    v0 += __shfl_xor(v0, 16); v0 += __shfl_xor(v0, 32);
    v1 += __shfl_xor(v1, 16); v1 += __shfl_xor(v1, 32);

    __shared__ double lg[4][2][E_NUM];
    if (ds == 0) {
        const double bias = (double)rb[e];
        lg[wave][0][e] = v0 + bias;
        lg[wave][1][e] = v1 + bias;
    }
    __syncthreads();

    if (lane < 2) {                     // lane t finishes token t0 + t
        const double* L = lg[wave][lane];
        double m = L[0];
#pragma unroll
        for (int k = 1; k < E_NUM; ++k) m = fmax(m, L[k]);

        int e1 = 0;
#pragma unroll
        for (int k = 1; k < E_NUM; ++k) if (L[k] > L[e1]) e1 = k;
        int e2 = (e1 == 0) ? 1 : 0;
        for (int k = 0; k < E_NUM; ++k)
            if (k != e1 && L[k] > L[e2]) e2 = k;

        float s = 0.0f;
#pragma unroll
        for (int k = 0; k < E_NUM; ++k) s = fmaf(expf((float)(L[k] - m)), 1.0f, s);
        const float w1 = expf((float)(L[e1] - m)) / s;
        const float w2 = expf((float)(L[e2] - m)) / s;

        const int n = t0 + lane;
        int pos1 = atomicAdd(&counts0[e1], 1);
        if (pos1 < CAP) entries0[e1 * CAP + pos1] = make_int2(n, __float_as_int(w1));
        int pos2 = atomicAdd(&counts1[e2], 1);
        if (pos2 < CAP) entries1[e2 * CAP + pos2] = make_int2(n, __float_as_int(w2));
    }
}

template <bool ADD>
__global__ __launch_bounds__(256) void moe_mfma_kernel(
    const float* __restrict__ x,
    const float* __restrict__ ew,
    const float* __restrict__ eb,
    const int* __restrict__ counts,
    const int2* __restrict__ entries,
    float* __restrict__ out)
{
    const int e = blockIdx.z;
    int count = counts[e];
    if (count > CAP) count = CAP;
    const int i0 = blockIdx.y * 128;
    if (i0 >= count) return;
    const int h0 = blockIdx.x * 128;

    __shared__ unsigned short Xs[128][KPAD];   // [token_row][k]
    __shared__ unsigned short Ws[128][KPAD];   // [h_col][k]  (W transposed)
    __shared__ int   s_tok[128];
    __shared__ float s_w[128];

    const int tid = threadIdx.x;
    if (tid < 128) {
        const int i = i0 + tid;
        if (i < count) {
            int2 en = entries[e * CAP + i];
            s_tok[tid] = en.x;
            s_w[tid] = __int_as_float(en.y);
        } else {
            s_tok[tid] = 0;
            s_w[tid] = 0.0f;
        }
    }
    __syncthreads();

    const int wave = tid >> 6;
    const int lane = tid & 63;
    const int wr = (wave >> 1) * 64;   // wave's token-row offset
    const int wc = (wave & 1) * 64;    // wave's h-col offset
    const int l15 = lane & 15;
    const int quad = lane >> 4;

    f32x4 acc[4][4] = {};   // [token 16-block][h 16-block]

    // A staging map: thread -> (k-quad, row set)
    const int a_kq = (tid & 7) * 4;    // k offset (float4)
    const int a_r0 = tid >> 3;         // 0..31, rows a_r0 + 32*it
    // B staging map: thread -> one h column, 16 k values
    const int b_n  = tid & 127;
    const int b_dh = (tid >> 7) * 16;  // 0 or 16

    const float* wcol = ew + (size_t)e * D_DIM * H_DIM + h0 + b_n;

    for (int d0 = 0; d0 < D_DIM; d0 += 32) {
        // ---- stage A: 128x32 fp32 -> bf16, row-major
#pragma unroll
        for (int it = 0; it < 4; ++it) {
            const int r = a_r0 + it * 32;
            const float4 v = *(const float4*)(x + (size_t)s_tok[r] * D_DIM + d0 + a_kq);
            ushort4 p;
            p.x = f2bf(v.x); p.y = f2bf(v.y); p.z = f2bf(v.z); p.w = f2bf(v.w);
            *(ushort4*)&Xs[r][a_kq] = p;   // 8B-aligned (80*r + 2*a_kq)
        }
        // ---- stage B: 32x128 fp32 -> bf16 transposed into Ws[n][k]
        {
            float t[16];
#pragma unroll
            for (int i = 0; i < 16; ++i)
                t[i] = wcol[(size_t)(d0 + b_dh + i) * H_DIM];
            uint4 lo, hi;
            lo.x = pk2bf(t[0], t[1]);  lo.y = pk2bf(t[2], t[3]);
            lo.z = pk2bf(t[4], t[5]);  lo.w = pk2bf(t[6], t[7]);
            hi.x = pk2bf(t[8], t[9]);  hi.y = pk2bf(t[10], t[11]);
            hi.z = pk2bf(t[12], t[13]); hi.w = pk2bf(t[14], t[15]);
            *(uint4*)&Ws[b_n][b_dh]     = lo;   // 16B-aligned (80*n + 2*b_dh)
            *(uint4*)&Ws[b_n][b_dh + 8] = hi;
        }
        __syncthreads();

        // ---- fragments + MFMA
        bf16x8 af[4], bq[4];
#pragma unroll
        for (int i = 0; i < 4; ++i)
            af[i] = *(const bf16x8*)&Xs[wr + i * 16 + l15][quad * 8];
#pragma unroll
        for (int j = 0; j < 4; ++j)
            bq[j] = *(const bf16x8*)&Ws[wc + j * 16 + l15][quad * 8];
#pragma unroll
        for (int i = 0; i < 4; ++i)
#pragma unroll
            for (int j = 0; j < 4; ++j)
                acc[i][j] = __builtin_amdgcn_mfma_f32_16x16x32_bf16(
                    af[i], bq[j], acc[i][j], 0, 0, 0);

        __syncthreads();
    }

    // ---- epilogue: D row = quad*4 + reg (token), col = l15 (h)
    float bias_j[4];
    const float* ebp = eb + e * H_DIM + h0 + wc;
#pragma unroll
    for (int j = 0; j < 4; ++j) bias_j[j] = ebp[j * 16 + l15];

#pragma unroll
    for (int i = 0; i < 4; ++i) {
#pragma unroll
        for (int r = 0; r < 4; ++r) {
            const int row = wr + i * 16 + quad * 4 + r;
            if (i0 + row < count) {
                const int tok = s_tok[row];
                const float w = s_w[row];
                float* op = out + (size_t)tok * H_DIM + h0 + wc + l15;
#pragma unroll
                for (int j = 0; j < 4; ++j) {
                    float v = w * (acc[i][j][r] + bias_j[j]);
                    if (ADD) v += op[j * 16];
                    op[j * 16] = v;
                }
            }
        }
    }
}

extern "C" void kernel_launch(void* const* d_in, const int* in_sizes, int n_in,
                              void* d_out, int out_size, void* d_ws, size_t ws_size,
                              hipStream_t stream)
{
    const float* x  = (const float*)d_in[0];
    const float* rw = (const float*)d_in[1];
    const float* rb = (const float*)d_in[2];
    const float* ew = (const float*)d_in[3];
    const float* eb = (const float*)d_in[4];

    char* ws = (char*)d_ws;
    int*  counts0  = (int*)ws;
    int*  counts1  = (int*)(ws + 64);
    int2* entries0 = (int2*)(ws + 1024);
    int2* entries1 = (int2*)(ws + 1024 + E_NUM * CAP * 8);

    hipMemsetAsync(ws, 0, 128, stream);

    router_kernel<<<N_TOK / 8, 256, 0, stream>>>(x, rw, rb, counts0, counts1,
                                                 entries0, entries1);

    dim3 grid(H_DIM / 128, CAP / 128, E_NUM);
    moe_mfma_kernel<false><<<grid, 256, 0, stream>>>(
        x, ew, eb, counts0, entries0, (float*)d_out);
    moe_mfma_kernel<true><<<grid, 256, 0, stream>>>(
        x, ew, eb, counts1, entries1, (float*)d_out);
}

// Round 3
// 332.930 us; speedup vs baseline: 1.2596x; 1.1724x over previous
//
#include <hip/hip_runtime.h>
#include <hip/hip_bf16.h>

// MoE block: N=8192, D=1024, H=1024, E=16, top-k=2. Inputs fp32, output fp32.
// out[n] = w1*(x@W_e1 + b_e1) + w2*(x@W_e2 + b_e2), w = top-2 of softmax.
//
// Round-8: global-atomic-free routing (round-7 retry). Round-6 post-mortem:
// router was bound by 16384 atomicAdds on TWO cache lines (counts0/counts1)
// -- one serialized L2 RMW per ~40cy ~= 120us, VALUBusy 6%. Now:
//   router_kernel: GEMV + top-2 only, writes res[n]={e1,e2,w1,w2} (no atomics)
//   build_lists:   16 blocks (1/expert) scan res[], compact via LDS atomics,
//                  write counts directly (no global atomics, no memset)
// Round-8 fix vs round-7: res[] is staged in d_out (first 128 KB of the 32 MB
// output), NOT in extra workspace -- round-7 grew ws usage by 128 KB beyond
// the footprint ever verified, the likely container-abort cause. Stream order
// makes this safe: router writes res -> build_lists consumes -> pass A
// overwrites every token row.
//
// Expert GEMM (unchanged): bf16 MFMA 16x16x32, 128x128 tile, BK=32,
// fp32->bf16 RNE during LDS staging, KPAD=40 rows.
//   pass A (ADD=0): slot-0 lists -> out = w*(x@W+b)   (covers every token)
//   pass B (ADD=1): slot-1 lists -> out += w*(x@W+b)  (fp32 RMW, race-free)

#define N_TOK 8192
#define D_DIM 1024
#define H_DIM 1024
#define E_NUM 16
#define CAP   1024
#define KPAD  40    // LDS row stride in ushorts (80 B)

typedef __attribute__((ext_vector_type(4))) float f32x4;
typedef __attribute__((ext_vector_type(8))) short bf16x8;

__device__ __forceinline__ unsigned short f2bf(float f) {
    unsigned int u = __float_as_uint(f);
    unsigned int r = u + 0x7fffu + ((u >> 16) & 1u);   // RNE
    return (unsigned short)(r >> 16);
}
__device__ __forceinline__ unsigned int pk2bf(float lo, float hi) {
    return (unsigned int)f2bf(lo) | ((unsigned int)f2bf(hi) << 16);
}

__global__ __launch_bounds__(256, 4) void router_kernel(
    const float* __restrict__ x,
    const float* __restrict__ rw,
    const float* __restrict__ rb,
    int4* __restrict__ res)
{
    const int wave = threadIdx.x >> 6;
    const int lane = threadIdx.x & 63;
    const int ds   = lane >> 4;        // D stripe 0..3 (owns d in [ds*256, ds*256+256))
    const int e    = lane & 15;        // expert
    const int t0   = blockIdx.x * 8 + wave * 2;   // this wave's two tokens

    const float* x0  = x + (size_t)t0 * D_DIM + ds * 256;
    const float* x1  = x0 + D_DIM;
    const float* rwp = rw + ds * 4096 + e;        // rw[(ds*256 + j)*16 + e]

    // fp32 inner FMA, drained into double every 32 terms (8 jb-iters x 4).
    double acc0 = 0.0, acc1 = 0.0;
#pragma unroll 2
    for (int g = 0; g < 8; ++g) {
        float s0 = 0.0f, s1 = 0.0f;
#pragma unroll
        for (int u = 0; u < 8; ++u) {
            const int jb = g * 8 + u;                       // 4 d's per jb
            const float4 a = *(const float4*)(x0 + jb * 4); // broadcast within 16-lane grp
            const float4 b = *(const float4*)(x1 + jb * 4);
            const float w0 = rwp[jb * 64];                  // d = ds*256 + jb*4 + 0
            const float w1 = rwp[jb * 64 + 16];             // ... + 1
            const float w2 = rwp[jb * 64 + 32];             // ... + 2
            const float w3 = rwp[jb * 64 + 48];             // ... + 3
            s0 = fmaf(a.w, w3, fmaf(a.z, w2, fmaf(a.y, w1, fmaf(a.x, w0, s0))));
            s1 = fmaf(b.w, w3, fmaf(b.z, w2, fmaf(b.y, w1, fmaf(b.x, w0, s1))));
        }
        acc0 += (double)s0;
        acc1 += (double)s1;
    }

    // reduce over the 4 d-stripes (lanes e, e+16, e+32, e+48) in double
    double v0 = acc0, v1 = acc1;
    v0 += __shfl_xor(v0, 16); v0 += __shfl_xor(v0, 32);
    v1 += __shfl_xor(v1, 16); v1 += __shfl_xor(v1, 32);

    __shared__ double lg[4][2][E_NUM];
    if (ds == 0) {
        const double bias = (double)rb[e];
        lg[wave][0][e] = v0 + bias;
        lg[wave][1][e] = v1 + bias;
    }
    __syncthreads();

    if (lane < 2) {                     // lane t finishes token t0 + t
        const double* L = lg[wave][lane];
        double m = L[0];
#pragma unroll
        for (int k = 1; k < E_NUM; ++k) m = fmax(m, L[k]);

        int e1 = 0;
#pragma unroll
        for (int k = 1; k < E_NUM; ++k) if (L[k] > L[e1]) e1 = k;
        int e2 = (e1 == 0) ? 1 : 0;
        for (int k = 0; k < E_NUM; ++k)
            if (k != e1 && L[k] > L[e2]) e2 = k;

        float s = 0.0f;
#pragma unroll
        for (int k = 0; k < E_NUM; ++k) s = fmaf(expf((float)(L[k] - m)), 1.0f, s);
        const float w1 = expf((float)(L[e1] - m)) / s;
        const float w2 = expf((float)(L[e2] - m)) / s;

        const int n = t0 + lane;
        res[n] = make_int4(e1, e2, __float_as_int(w1), __float_as_int(w2));
    }
}

__global__ __launch_bounds__(256) void build_lists(
    const int4* __restrict__ res,
    int* __restrict__ counts0, int* __restrict__ counts1,
    int2* __restrict__ entries0, int2* __restrict__ entries1)
{
    const int e = blockIdx.x;
    __shared__ int c0, c1;
    if (threadIdx.x == 0) { c0 = 0; c1 = 0; }
    __syncthreads();

    for (int i = threadIdx.x; i < N_TOK; i += 256) {
        const int4 r = res[i];
        if (r.x == e) {
            int p = atomicAdd(&c0, 1);
            if (p < CAP) entries0[e * CAP + p] = make_int2(i, r.z);
        }
        if (r.y == e) {
            int p = atomicAdd(&c1, 1);
            if (p < CAP) entries1[e * CAP + p] = make_int2(i, r.w);
        }
    }
    __syncthreads();
    if (threadIdx.x == 0) { counts0[e] = c0; counts1[e] = c1; }
}

template <bool ADD>
__global__ __launch_bounds__(256) void moe_mfma_kernel(
    const float* __restrict__ x,
    const float* __restrict__ ew,
    const float* __restrict__ eb,
    const int* __restrict__ counts,
    const int2* __restrict__ entries,
    float* __restrict__ out)
{
    const int e = blockIdx.z;
    int count = counts[e];
    if (count > CAP) count = CAP;
    const int i0 = blockIdx.y * 128;
    if (i0 >= count) return;
    const int h0 = blockIdx.x * 128;

    __shared__ unsigned short Xs[128][KPAD];   // [token_row][k]
    __shared__ unsigned short Ws[128][KPAD];   // [h_col][k]  (W transposed)
    __shared__ int   s_tok[128];
    __shared__ float s_w[128];

    const int tid = threadIdx.x;
    if (tid < 128) {
        const int i = i0 + tid;
        if (i < count) {
            int2 en = entries[e * CAP + i];
            s_tok[tid] = en.x;
            s_w[tid] = __int_as_float(en.y);
        } else {
            s_tok[tid] = 0;
            s_w[tid] = 0.0f;
        }
    }
    __syncthreads();

    const int wave = tid >> 6;
    const int lane = tid & 63;
    const int wr = (wave >> 1) * 64;   // wave's token-row offset
    const int wc = (wave & 1) * 64;    // wave's h-col offset
    const int l15 = lane & 15;
    const int quad = lane >> 4;

    f32x4 acc[4][4] = {};   // [token 16-block][h 16-block]

    // A staging map: thread -> (k-quad, row set)
    const int a_kq = (tid & 7) * 4;    // k offset (float4)
    const int a_r0 = tid >> 3;         // 0..31, rows a_r0 + 32*it
    // B staging map: thread -> one h column, 16 k values
    const int b_n  = tid & 127;
    const int b_dh = (tid >> 7) * 16;  // 0 or 16

    const float* wcol = ew + (size_t)e * D_DIM * H_DIM + h0 + b_n;

    for (int d0 = 0; d0 < D_DIM; d0 += 32) {
        // ---- stage A: 128x32 fp32 -> bf16, row-major
#pragma unroll
        for (int it = 0; it < 4; ++it) {
            const int r = a_r0 + it * 32;
            const float4 v = *(const float4*)(x + (size_t)s_tok[r] * D_DIM + d0 + a_kq);
            ushort4 p;
            p.x = f2bf(v.x); p.y = f2bf(v.y); p.z = f2bf(v.z); p.w = f2bf(v.w);
            *(ushort4*)&Xs[r][a_kq] = p;   // 8B-aligned (80*r + 2*a_kq)
        }
        // ---- stage B: 32x128 fp32 -> bf16 transposed into Ws[n][k]
        {
            float t[16];
#pragma unroll
            for (int i = 0; i < 16; ++i)
                t[i] = wcol[(size_t)(d0 + b_dh + i) * H_DIM];
            uint4 lo, hi;
            lo.x = pk2bf(t[0], t[1]);  lo.y = pk2bf(t[2], t[3]);
            lo.z = pk2bf(t[4], t[5]);  lo.w = pk2bf(t[6], t[7]);
            hi.x = pk2bf(t[8], t[9]);  hi.y = pk2bf(t[10], t[11]);
            hi.z = pk2bf(t[12], t[13]); hi.w = pk2bf(t[14], t[15]);
            *(uint4*)&Ws[b_n][b_dh]     = lo;   // 16B-aligned (80*n + 2*b_dh)
            *(uint4*)&Ws[b_n][b_dh + 8] = hi;
        }
        __syncthreads();

        // ---- fragments + MFMA
        bf16x8 af[4], bq[4];
#pragma unroll
        for (int i = 0; i < 4; ++i)
            af[i] = *(const bf16x8*)&Xs[wr + i * 16 + l15][quad * 8];
#pragma unroll
        for (int j = 0; j < 4; ++j)
            bq[j] = *(const bf16x8*)&Ws[wc + j * 16 + l15][quad * 8];
#pragma unroll
        for (int i = 0; i < 4; ++i)
#pragma unroll
            for (int j = 0; j < 4; ++j)
                acc[i][j] = __builtin_amdgcn_mfma_f32_16x16x32_bf16(
                    af[i], bq[j], acc[i][j], 0, 0, 0);

        __syncthreads();
    }

    // ---- epilogue: D row = quad*4 + reg (token), col = l15 (h)
    float bias_j[4];
    const float* ebp = eb + e * H_DIM + h0 + wc;
#pragma unroll
    for (int j = 0; j < 4; ++j) bias_j[j] = ebp[j * 16 + l15];

#pragma unroll
    for (int i = 0; i < 4; ++i) {
#pragma unroll
        for (int r = 0; r < 4; ++r) {
            const int row = wr + i * 16 + quad * 4 + r;
            if (i0 + row < count) {
                const int tok = s_tok[row];
                const float w = s_w[row];
                float* op = out + (size_t)tok * H_DIM + h0 + wc + l15;
#pragma unroll
                for (int j = 0; j < 4; ++j) {
                    float v = w * (acc[i][j][r] + bias_j[j]);
                    if (ADD) v += op[j * 16];
                    op[j * 16] = v;
                }
            }
        }
    }
}

extern "C" void kernel_launch(void* const* d_in, const int* in_sizes, int n_in,
                              void* d_out, int out_size, void* d_ws, size_t ws_size,
                              hipStream_t stream)
{
    const float* x  = (const float*)d_in[0];
    const float* rw = (const float*)d_in[1];
    const float* rb = (const float*)d_in[2];
    const float* ew = (const float*)d_in[3];
    const float* eb = (const float*)d_in[4];

    char* ws = (char*)d_ws;
    int*  counts0  = (int*)ws;
    int*  counts1  = (int*)(ws + 64);
    int2* entries0 = (int2*)(ws + 1024);
    int2* entries1 = (int2*)(ws + 1024 + E_NUM * CAP * 8);

    // res[] staged in d_out (128 KB of the 32 MB output buffer). Stream
    // order: router writes res -> build_lists consumes -> pass A overwrites
    // every token row. Keeps ws footprint identical to the verified layout.
    int4* res = (int4*)d_out;

    router_kernel<<<N_TOK / 8, 256, 0, stream>>>(x, rw, rb, res);

    build_lists<<<E_NUM, 256, 0, stream>>>(res, counts0, counts1,
                                           entries0, entries1);

    dim3 grid(H_DIM / 128, CAP / 128, E_NUM);
    moe_mfma_kernel<false><<<grid, 256, 0, stream>>>(
        x, ew, eb, counts0, entries0, (float*)d_out);
    moe_mfma_kernel<true><<<grid, 256, 0, stream>>>(
        x, ew, eb, counts1, entries1, (float*)d_out);
}

// Round 5
// 330.429 us; speedup vs baseline: 1.2692x; 1.0076x over previous
//
#include <hip/hip_runtime.h>
#include <hip/hip_bf16.h>

// MoE block: N=8192, D=1024, H=1024, E=16, top-k=2. Inputs fp32, output fp32.
// out[n] = w1*(x@W_e1 + b_e1) + w2*(x@W_e2 + b_e2), w = top-2 of softmax.
//
// Round-10: RESUBMIT of round-9 (container failed; audit found no kernel
// fault -- all barriers uniform, LDS 42KB aligned accesses, bounded reads;
// round-3 timing showed infra instability, e.g. push_in_npz_s=776s).
// If this fails twice-in-a-row again, the kernel is implicated: next step
// would be revert to round-8 MFMA structure + add changes one at a time.
//
// Round-9 changes vs round-8 (MoE kernel only; router/build_lists unchanged):
//   * register prefetch of next K-tile (4x float4 A + 16x f32 W) issued
//     right after the barrier, consumed (cvt+ds_write) after the MFMAs
//   * double-buffered LDS, ONE barrier per K-step (read cur / write nxt)
//   * token-row pointers hoisted out of the K-loop (less addr VALU)
//   * XCD-aware swizzle: 1-D grid 1024, lid=(flat&7)*128+flat>>3 ->
//     each XCD owns 2 experts; X/W tiles fetched once per XCD L2 (m204)
//   pass A (ADD=0): slot-0 lists -> out = w*(x@W+b)   (covers every token)
//   pass B (ADD=1): slot-1 lists -> out += w*(x@W+b)  (fp32 RMW, race-free)

#define N_TOK 8192
#define D_DIM 1024
#define H_DIM 1024
#define E_NUM 16
#define CAP   1024
#define KPAD  40    // LDS row stride in ushorts (80 B)

typedef __attribute__((ext_vector_type(4))) float f32x4;
typedef __attribute__((ext_vector_type(8))) short bf16x8;

__device__ __forceinline__ unsigned short f2bf(float f) {
    unsigned int u = __float_as_uint(f);
    unsigned int r = u + 0x7fffu + ((u >> 16) & 1u);   // RNE
    return (unsigned short)(r >> 16);
}
__device__ __forceinline__ unsigned int pk2bf(float lo, float hi) {
    return (unsigned int)f2bf(lo) | ((unsigned int)f2bf(hi) << 16);
}

__global__ __launch_bounds__(256, 4) void router_kernel(
    const float* __restrict__ x,
    const float* __restrict__ rw,
    const float* __restrict__ rb,
    int4* __restrict__ res)
{
    const int wave = threadIdx.x >> 6;
    const int lane = threadIdx.x & 63;
    const int ds   = lane >> 4;        // D stripe 0..3 (owns d in [ds*256, ds*256+256))
    const int e    = lane & 15;        // expert
    const int t0   = blockIdx.x * 8 + wave * 2;   // this wave's two tokens

    const float* x0  = x + (size_t)t0 * D_DIM + ds * 256;
    const float* x1  = x0 + D_DIM;
    const float* rwp = rw + ds * 4096 + e;        // rw[(ds*256 + j)*16 + e]

    // fp32 inner FMA, drained into double every 32 terms (8 jb-iters x 4).
    double acc0 = 0.0, acc1 = 0.0;
#pragma unroll 2
    for (int g = 0; g < 8; ++g) {
        float s0 = 0.0f, s1 = 0.0f;
#pragma unroll
        for (int u = 0; u < 8; ++u) {
            const int jb = g * 8 + u;                       // 4 d's per jb
            const float4 a = *(const float4*)(x0 + jb * 4); // broadcast within 16-lane grp
            const float4 b = *(const float4*)(x1 + jb * 4);
            const float w0 = rwp[jb * 64];                  // d = ds*256 + jb*4 + 0
            const float w1 = rwp[jb * 64 + 16];             // ... + 1
            const float w2 = rwp[jb * 64 + 32];             // ... + 2
            const float w3 = rwp[jb * 64 + 48];             // ... + 3
            s0 = fmaf(a.w, w3, fmaf(a.z, w2, fmaf(a.y, w1, fmaf(a.x, w0, s0))));
            s1 = fmaf(b.w, w3, fmaf(b.z, w2, fmaf(b.y, w1, fmaf(b.x, w0, s1))));
        }
        acc0 += (double)s0;
        acc1 += (double)s1;
    }

    // reduce over the 4 d-stripes (lanes e, e+16, e+32, e+48) in double
    double v0 = acc0, v1 = acc1;
    v0 += __shfl_xor(v0, 16); v0 += __shfl_xor(v0, 32);
    v1 += __shfl_xor(v1, 16); v1 += __shfl_xor(v1, 32);

    __shared__ double lg[4][2][E_NUM];
    if (ds == 0) {
        const double bias = (double)rb[e];
        lg[wave][0][e] = v0 + bias;
        lg[wave][1][e] = v1 + bias;
    }
    __syncthreads();

    if (lane < 2) {                     // lane t finishes token t0 + t
        const double* L = lg[wave][lane];
        double m = L[0];
#pragma unroll
        for (int k = 1; k < E_NUM; ++k) m = fmax(m, L[k]);

        int e1 = 0;
#pragma unroll
        for (int k = 1; k < E_NUM; ++k) if (L[k] > L[e1]) e1 = k;
        int e2 = (e1 == 0) ? 1 : 0;
        for (int k = 0; k < E_NUM; ++k)
            if (k != e1 && L[k] > L[e2]) e2 = k;

        float s = 0.0f;
#pragma unroll
        for (int k = 0; k < E_NUM; ++k) s = fmaf(expf((float)(L[k] - m)), 1.0f, s);
        const float w1 = expf((float)(L[e1] - m)) / s;
        const float w2 = expf((float)(L[e2] - m)) / s;

        const int n = t0 + lane;
        res[n] = make_int4(e1, e2, __float_as_int(w1), __float_as_int(w2));
    }
}

__global__ __launch_bounds__(256) void build_lists(
    const int4* __restrict__ res,
    int* __restrict__ counts0, int* __restrict__ counts1,
    int2* __restrict__ entries0, int2* __restrict__ entries1)
{
    const int e = blockIdx.x;
    __shared__ int c0, c1;
    if (threadIdx.x == 0) { c0 = 0; c1 = 0; }
    __syncthreads();

    for (int i = threadIdx.x; i < N_TOK; i += 256) {
        const int4 r = res[i];
        if (r.x == e) {
            int p = atomicAdd(&c0, 1);
            if (p < CAP) entries0[e * CAP + p] = make_int2(i, r.z);
        }
        if (r.y == e) {
            int p = atomicAdd(&c1, 1);
            if (p < CAP) entries1[e * CAP + p] = make_int2(i, r.w);
        }
    }
    __syncthreads();
    if (threadIdx.x == 0) { counts0[e] = c0; counts1[e] = c1; }
}

template <bool ADD>
__global__ __launch_bounds__(256) void moe_mfma_kernel(
    const float* __restrict__ x,
    const float* __restrict__ ew,
    const float* __restrict__ eb,
    const int* __restrict__ counts,
    const int2* __restrict__ entries,
    float* __restrict__ out)
{
    // XCD swizzle (m204-style): consecutive HW block IDs round-robin XCDs;
    // remap so each XCD gets a contiguous 128-chunk of logical work = 2 experts.
    const int flat = blockIdx.x;                    // 0..1023
    const int lid  = (flat & 7) * 128 + (flat >> 3);
    const int h0 = (lid & 7) * 128;
    const int i0 = ((lid >> 3) & 7) * 128;
    const int e  = lid >> 6;

    int count = counts[e];
    if (count > CAP) count = CAP;
    if (i0 >= count) return;

    __shared__ unsigned short Xs[2][128][KPAD];   // [buf][token_row][k]
    __shared__ unsigned short Ws[2][128][KPAD];   // [buf][h_col][k]  (W transposed)
    __shared__ int   s_tok[128];
    __shared__ float s_w[128];

    const int tid = threadIdx.x;
    if (tid < 128) {
        const int i = i0 + tid;
        if (i < count) {
            int2 en = entries[e * CAP + i];
            s_tok[tid] = en.x;
            s_w[tid] = __int_as_float(en.y);
        } else {
            s_tok[tid] = 0;
            s_w[tid] = 0.0f;
        }
    }
    __syncthreads();

    const int wave = tid >> 6;
    const int lane = tid & 63;
    const int wr = (wave >> 1) * 64;   // wave's token-row offset
    const int wc = (wave & 1) * 64;    // wave's h-col offset
    const int l15 = lane & 15;
    const int quad = lane >> 4;

    f32x4 acc[4][4] = {};   // [token 16-block][h 16-block]

    // A staging map: thread -> (k-quad, row set)
    const int a_kq = (tid & 7) * 4;    // k offset (float4)
    const int a_r0 = tid >> 3;         // 0..31, rows a_r0 + 32*it
    // B staging map: thread -> one h column, 16 k values
    const int b_n  = tid & 127;
    const int b_dh = (tid >> 7) * 16;  // 0 or 16

    // hoisted per-thread global pointers (fixed across the K loop)
    const float* ap[4];
#pragma unroll
    for (int it = 0; it < 4; ++it)
        ap[it] = x + (size_t)s_tok[a_r0 + it * 32] * D_DIM + a_kq;
    const float* bp = ew + (size_t)e * D_DIM * H_DIM
                    + (size_t)b_dh * H_DIM + h0 + b_n;   // element k=d0+b_dh+i at bp+(d0+i)*H

    // ---- prefetch tile 0 into registers
    float4 pa[4];
    float  pb[16];
#pragma unroll
    for (int it = 0; it < 4; ++it) pa[it] = *(const float4*)(ap[it]);
#pragma unroll
    for (int i = 0; i < 16; ++i)  pb[i] = bp[(size_t)i * H_DIM];

    // ---- write tile 0 -> buf 0
    {
#pragma unroll
        for (int it = 0; it < 4; ++it) {
            ushort4 p;
            p.x = f2bf(pa[it].x); p.y = f2bf(pa[it].y);
            p.z = f2bf(pa[it].z); p.w = f2bf(pa[it].w);
            *(ushort4*)&Xs[0][a_r0 + it * 32][a_kq] = p;
        }
        uint4 lo, hi;
        lo.x = pk2bf(pb[0], pb[1]);   lo.y = pk2bf(pb[2], pb[3]);
        lo.z = pk2bf(pb[4], pb[5]);   lo.w = pk2bf(pb[6], pb[7]);
        hi.x = pk2bf(pb[8], pb[9]);   hi.y = pk2bf(pb[10], pb[11]);
        hi.z = pk2bf(pb[12], pb[13]); hi.w = pk2bf(pb[14], pb[15]);
        *(uint4*)&Ws[0][b_n][b_dh]     = lo;
        *(uint4*)&Ws[0][b_n][b_dh + 8] = hi;
    }

    int cur = 0;
    for (int d0 = 0; d0 < D_DIM; d0 += 32) {
        __syncthreads();                       // buf[cur] ready; buf[cur^1] free
        const bool more = (d0 + 32 < D_DIM);

        // ---- issue next tile's global loads (latency hides under MFMAs)
        if (more) {
#pragma unroll
            for (int it = 0; it < 4; ++it)
                pa[it] = *(const float4*)(ap[it] + d0 + 32);
#pragma unroll
            for (int i = 0; i < 16; ++i)
                pb[i] = bp[(size_t)(d0 + 32 + i) * H_DIM];
        }

        // ---- fragments + MFMA on buf[cur]
        bf16x8 af[4], bq[4];
#pragma unroll
        for (int i = 0; i < 4; ++i)
            af[i] = *(const bf16x8*)&Xs[cur][wr + i * 16 + l15][quad * 8];
#pragma unroll
        for (int j = 0; j < 4; ++j)
            bq[j] = *(const bf16x8*)&Ws[cur][wc + j * 16 + l15][quad * 8];
#pragma unroll
        for (int i = 0; i < 4; ++i)
#pragma unroll
            for (int j = 0; j < 4; ++j)
                acc[i][j] = __builtin_amdgcn_mfma_f32_16x16x32_bf16(
                    af[i], bq[j], acc[i][j], 0, 0, 0);

        // ---- convert + write next tile into buf[cur^1]
        if (more) {
            const int nxt = cur ^ 1;
#pragma unroll
            for (int it = 0; it < 4; ++it) {
                ushort4 p;
                p.x = f2bf(pa[it].x); p.y = f2bf(pa[it].y);
                p.z = f2bf(pa[it].z); p.w = f2bf(pa[it].w);
                *(ushort4*)&Xs[nxt][a_r0 + it * 32][a_kq] = p;
            }
            uint4 lo, hi;
            lo.x = pk2bf(pb[0], pb[1]);   lo.y = pk2bf(pb[2], pb[3]);
            lo.z = pk2bf(pb[4], pb[5]);   lo.w = pk2bf(pb[6], pb[7]);
            hi.x = pk2bf(pb[8], pb[9]);   hi.y = pk2bf(pb[10], pb[11]);
            hi.z = pk2bf(pb[12], pb[13]); hi.w = pk2bf(pb[14], pb[15]);
            *(uint4*)&Ws[nxt][b_n][b_dh]     = lo;
            *(uint4*)&Ws[nxt][b_n][b_dh + 8] = hi;
        }
        cur ^= 1;
    }

    // ---- epilogue: D row = quad*4 + reg (token), col = l15 (h)
    float bias_j[4];
    const float* ebp = eb + e * H_DIM + h0 + wc;
#pragma unroll
    for (int j = 0; j < 4; ++j) bias_j[j] = ebp[j * 16 + l15];

#pragma unroll
    for (int i = 0; i < 4; ++i) {
#pragma unroll
        for (int r = 0; r < 4; ++r) {
            const int row = wr + i * 16 + quad * 4 + r;
            if (i0 + row < count) {
                const int tok = s_tok[row];
                const float w = s_w[row];
                float* op = out + (size_t)tok * H_DIM + h0 + wc + l15;
#pragma unroll
                for (int j = 0; j < 4; ++j) {
                    float v = w * (acc[i][j][r] + bias_j[j]);
                    if (ADD) v += op[j * 16];
                    op[j * 16] = v;
                }
            }
        }
    }
}

extern "C" void kernel_launch(void* const* d_in, const int* in_sizes, int n_in,
                              void* d_out, int out_size, void* d_ws, size_t ws_size,
                              hipStream_t stream)
{
    const float* x  = (const float*)d_in[0];
    const float* rw = (const float*)d_in[1];
    const float* rb = (const float*)d_in[2];
    const float* ew = (const float*)d_in[3];
    const float* eb = (const float*)d_in[4];

    char* ws = (char*)d_ws;
    int*  counts0  = (int*)ws;
    int*  counts1  = (int*)(ws + 64);
    int2* entries0 = (int2*)(ws + 1024);
    int2* entries1 = (int2*)(ws + 1024 + E_NUM * CAP * 8);

    // res[] staged in d_out (128 KB of the 32 MB output buffer). Stream
    // order: router writes res -> build_lists consumes -> pass A overwrites
    // every token row. Keeps ws footprint identical to the verified layout.
    int4* res = (int4*)d_out;

    router_kernel<<<N_TOK / 8, 256, 0, stream>>>(x, rw, rb, res);

    build_lists<<<E_NUM, 256, 0, stream>>>(res, counts0, counts1,
                                           entries0, entries1);

    // 1-D grid, XCD-swizzled inside the kernel (1024 logical blocks/pass)
    moe_mfma_kernel<false><<<1024, 256, 0, stream>>>(
        x, ew, eb, counts0, entries0, (float*)d_out);
    moe_mfma_kernel<true><<<1024, 256, 0, stream>>>(
        x, ew, eb, counts1, entries1, (float*)d_out);
}

// Round 6
// 285.322 us; speedup vs baseline: 1.4698x; 1.1581x over previous
//
#include <hip/hip_runtime.h>
#include <hip/hip_bf16.h>

// MoE block: N=8192, D=1024, H=1024, E=16, top-k=2. Inputs fp32, output fp32.
// out[n] = w1*(x@W_e1 + b_e1) + w2*(x@W_e2 + b_e2), w = top-2 of softmax.
//
// Round-11: kill the conversion VALU + occupancy starvation. R10 counters:
// MfmaUtil 7.3%, VALUBusy 32%, hbm 13.7%, occ 13.5% -- GEMM is bound by
// re-converting fp32->bf16 at every tile staging (~16x per X row across
// h-blocks/passes) with ~1 wave/SIMD to hide it.
//   cvt_kernel:   once per call, Xb=bf16(X) [N][D]; Wt=bf16(W) transposed
//                 [E][H][D] via 64x64 LDS tile transpose. ~25us, amortized.
//   moe_gemm_bf16: stages pure bf16 16B loads (no cvt), dense in-kernel
//                 worklist (prefix over counts -> only existing i-chunks,
//                 no early-exit waste, balanced).
//   ws guard:     needs 49MB; if ws_size too small, falls back to the
//                 proven R10 path (no crash risk).
//   pass A (ADD=0): slot-0 lists -> out = w*(x@W+b)   (covers every token)
//   pass B (ADD=1): slot-1 lists -> out += w*(x@W+b)  (fp32 RMW, race-free)

#define N_TOK 8192
#define D_DIM 1024
#define H_DIM 1024
#define E_NUM 16
#define CAP   1024
#define KPAD  40    // LDS row stride in ushorts (80 B)

typedef __attribute__((ext_vector_type(4))) float f32x4;
typedef __attribute__((ext_vector_type(8))) short bf16x8;

__device__ __forceinline__ unsigned short f2bf(float f) {
    unsigned int u = __float_as_uint(f);
    unsigned int r = u + 0x7fffu + ((u >> 16) & 1u);   // RNE
    return (unsigned short)(r >> 16);
}
__device__ __forceinline__ unsigned int pk2bf(float lo, float hi) {
    return (unsigned int)f2bf(lo) | ((unsigned int)f2bf(hi) << 16);
}

// ---------------- router (unchanged from R10) ----------------
__global__ __launch_bounds__(256, 4) void router_kernel(
    const float* __restrict__ x,
    const float* __restrict__ rw,
    const float* __restrict__ rb,
    int4* __restrict__ res)
{
    const int wave = threadIdx.x >> 6;
    const int lane = threadIdx.x & 63;
    const int ds   = lane >> 4;
    const int e    = lane & 15;
    const int t0   = blockIdx.x * 8 + wave * 2;

    const float* x0  = x + (size_t)t0 * D_DIM + ds * 256;
    const float* x1  = x0 + D_DIM;
    const float* rwp = rw + ds * 4096 + e;

    double acc0 = 0.0, acc1 = 0.0;
#pragma unroll 2
    for (int g = 0; g < 8; ++g) {
        float s0 = 0.0f, s1 = 0.0f;
#pragma unroll
        for (int u = 0; u < 8; ++u) {
            const int jb = g * 8 + u;
            const float4 a = *(const float4*)(x0 + jb * 4);
            const float4 b = *(const float4*)(x1 + jb * 4);
            const float w0 = rwp[jb * 64];
            const float w1 = rwp[jb * 64 + 16];
            const float w2 = rwp[jb * 64 + 32];
            const float w3 = rwp[jb * 64 + 48];
            s0 = fmaf(a.w, w3, fmaf(a.z, w2, fmaf(a.y, w1, fmaf(a.x, w0, s0))));
            s1 = fmaf(b.w, w3, fmaf(b.z, w2, fmaf(b.y, w1, fmaf(b.x, w0, s1))));
        }
        acc0 += (double)s0;
        acc1 += (double)s1;
    }

    double v0 = acc0, v1 = acc1;
    v0 += __shfl_xor(v0, 16); v0 += __shfl_xor(v0, 32);
    v1 += __shfl_xor(v1, 16); v1 += __shfl_xor(v1, 32);

    __shared__ double lg[4][2][E_NUM];
    if (ds == 0) {
        const double bias = (double)rb[e];
        lg[wave][0][e] = v0 + bias;
        lg[wave][1][e] = v1 + bias;
    }
    __syncthreads();

    if (lane < 2) {
        const double* L = lg[wave][lane];
        double m = L[0];
#pragma unroll
        for (int k = 1; k < E_NUM; ++k) m = fmax(m, L[k]);

        int e1 = 0;
#pragma unroll
        for (int k = 1; k < E_NUM; ++k) if (L[k] > L[e1]) e1 = k;
        int e2 = (e1 == 0) ? 1 : 0;
        for (int k = 0; k < E_NUM; ++k)
            if (k != e1 && L[k] > L[e2]) e2 = k;

        float s = 0.0f;
#pragma unroll
        for (int k = 0; k < E_NUM; ++k) s = fmaf(expf((float)(L[k] - m)), 1.0f, s);
        const float w1 = expf((float)(L[e1] - m)) / s;
        const float w2 = expf((float)(L[e2] - m)) / s;

        const int n = t0 + lane;
        res[n] = make_int4(e1, e2, __float_as_int(w1), __float_as_int(w2));
    }
}

// ---------------- build_lists (unchanged from R10) ----------------
__global__ __launch_bounds__(256) void build_lists(
    const int4* __restrict__ res,
    int* __restrict__ counts0, int* __restrict__ counts1,
    int2* __restrict__ entries0, int2* __restrict__ entries1)
{
    const int e = blockIdx.x;
    __shared__ int c0, c1;
    if (threadIdx.x == 0) { c0 = 0; c1 = 0; }
    __syncthreads();

    for (int i = threadIdx.x; i < N_TOK; i += 256) {
        const int4 r = res[i];
        if (r.x == e) {
            int p = atomicAdd(&c0, 1);
            if (p < CAP) entries0[e * CAP + p] = make_int2(i, r.z);
        }
        if (r.y == e) {
            int p = atomicAdd(&c1, 1);
            if (p < CAP) entries1[e * CAP + p] = make_int2(i, r.w);
        }
    }
    __syncthreads();
    if (threadIdx.x == 0) { counts0[e] = c0; counts1[e] = c1; }
}

// ---------------- cvt: Xb = bf16(X); Wt = bf16(W) transposed ----------------
// blocks [0,4096): X elementwise, 8 floats/thread.
// blocks [4096,8192): W 64x64 tile transpose through LDS.
__global__ __launch_bounds__(256) void cvt_kernel(
    const float* __restrict__ x,
    const float* __restrict__ ew,
    unsigned short* __restrict__ xb,
    unsigned short* __restrict__ wt)
{
    const int tid = threadIdx.x;
    if (blockIdx.x < 4096) {
        const size_t base = ((size_t)blockIdx.x * 256 + tid) * 8;
        const float4 a = *(const float4*)(x + base);
        const float4 b = *(const float4*)(x + base + 4);
        uint4 p;
        p.x = pk2bf(a.x, a.y); p.y = pk2bf(a.z, a.w);
        p.z = pk2bf(b.x, b.y); p.w = pk2bf(b.z, b.w);
        *(uint4*)(xb + base) = p;
        return;
    }
    __shared__ unsigned short Ts[64][68];
    const int wi = blockIdx.x - 4096;        // 0..4095
    const int e  = wi >> 8;                   // 256 tiles/expert
    const int kt = (wi >> 4) & 15;
    const int ht = wi & 15;

    // read: 64 k-rows x 64 h, coalesced float4, convert, store [k][h]
    {
        const int kl0 = tid >> 4;             // 0..15 (+16*i)
        const int hl  = (tid & 15) * 4;
        const float* src = ew + (size_t)e * (D_DIM * H_DIM)
                         + (size_t)(kt * 64 + kl0) * H_DIM + ht * 64 + hl;
#pragma unroll
        for (int i = 0; i < 4; ++i) {
            const float4 v = *(const float4*)(src + (size_t)i * 16 * H_DIM);
            ushort4 p;
            p.x = f2bf(v.x); p.y = f2bf(v.y); p.z = f2bf(v.z); p.w = f2bf(v.w);
            *(ushort4*)&Ts[kl0 + i * 16][hl] = p;    // (k*68+h)*2: 8B-aligned
        }
    }
    __syncthreads();
    // write: 64 h-rows x 64 k, transposed gather from LDS, 32B/thread
    {
        const int h2 = tid >> 2;              // 0..63
        const int kc = (tid & 3) * 16;
        unsigned int r[8];
#pragma unroll
        for (int i = 0; i < 8; ++i)
            r[i] = (unsigned int)Ts[kc + 2 * i][h2]
                 | ((unsigned int)Ts[kc + 2 * i + 1][h2] << 16);
        unsigned short* dst = wt + (size_t)e * (D_DIM * H_DIM)
                            + (size_t)(ht * 64 + h2) * D_DIM + kt * 64 + kc;
        *(uint4*)dst       = *(uint4*)&r[0];
        *(uint4*)(dst + 8) = *(uint4*)&r[4];
    }
}

// ---------------- GEMM from precached bf16, dense worklist ----------------
template <bool ADD>
__global__ __launch_bounds__(256) void moe_gemm_bf16(
    const unsigned short* __restrict__ xb,   // [N][D] bf16
    const unsigned short* __restrict__ wt,   // [E][H][D] bf16
    const float* __restrict__ eb,
    const int* __restrict__ counts,
    const int2* __restrict__ entries,
    float* __restrict__ out)
{
    // dense worklist: block -> (e, i-chunk, h) over existing i-chunks only
    int e = 0, loc = blockIdx.x, count = 0;
    for (; e < E_NUM; ++e) {
        int c = counts[e]; if (c > CAP) c = CAP;
        const int nb = ((c + 127) >> 7) << 3;   // ceil(c/128) * 8 h-blocks
        if (loc < nb) { count = c; break; }
        loc -= nb;
    }
    if (e == E_NUM) return;
    const int i0 = (loc >> 3) * 128;
    const int h0 = (loc & 7) * 128;

    __shared__ unsigned short Xs[2][128][KPAD];
    __shared__ unsigned short Ws[2][128][KPAD];
    __shared__ int   s_tok[128];
    __shared__ float s_w[128];

    const int tid = threadIdx.x;
    if (tid < 128) {
        const int i = i0 + tid;
        if (i < count) {
            int2 en = entries[e * CAP + i];
            s_tok[tid] = en.x;
            s_w[tid] = __int_as_float(en.y);
        } else {
            s_tok[tid] = 0;
            s_w[tid] = 0.0f;
        }
    }
    __syncthreads();

    const int wave = tid >> 6;
    const int lane = tid & 63;
    const int wr = (wave >> 1) * 64;
    const int wc = (wave & 1) * 64;
    const int l15 = lane & 15;
    const int quad = lane >> 4;

    f32x4 acc[4][4] = {};

    // staging map: thread -> (row 0..127, 16-ushort half)
    const int row  = tid >> 1;
    const int half = (tid & 1) * 16;
    const unsigned short* xp = xb + (size_t)s_tok[row] * D_DIM + half;
    const unsigned short* wp = wt + (size_t)(e * H_DIM + h0 + row) * D_DIM + half;

    // prefetch tile 0 -> regs -> buf 0
    uint4 pa0 = *(const uint4*)(xp);
    uint4 pa1 = *(const uint4*)(xp + 8);
    uint4 pw0 = *(const uint4*)(wp);
    uint4 pw1 = *(const uint4*)(wp + 8);
    *(uint4*)&Xs[0][row][half]     = pa0;
    *(uint4*)&Xs[0][row][half + 8] = pa1;
    *(uint4*)&Ws[0][row][half]     = pw0;
    *(uint4*)&Ws[0][row][half + 8] = pw1;

    int cur = 0;
    for (int d0 = 0; d0 < D_DIM; d0 += 32) {
        __syncthreads();                       // buf[cur] ready
        const bool more = (d0 + 32 < D_DIM);

        if (more) {                            // issue next-tile loads
            pa0 = *(const uint4*)(xp + d0 + 32);
            pa1 = *(const uint4*)(xp + d0 + 40);
            pw0 = *(const uint4*)(wp + d0 + 32);
            pw1 = *(const uint4*)(wp + d0 + 40);
        }

        bf16x8 af[4], bq[4];
#pragma unroll
        for (int i = 0; i < 4; ++i)
            af[i] = *(const bf16x8*)&Xs[cur][wr + i * 16 + l15][quad * 8];
#pragma unroll
        for (int j = 0; j < 4; ++j)
            bq[j] = *(const bf16x8*)&Ws[cur][wc + j * 16 + l15][quad * 8];
#pragma unroll
        for (int i = 0; i < 4; ++i)
#pragma unroll
            for (int j = 0; j < 4; ++j)
                acc[i][j] = __builtin_amdgcn_mfma_f32_16x16x32_bf16(
                    af[i], bq[j], acc[i][j], 0, 0, 0);

        if (more) {                            // write next tile
            const int nxt = cur ^ 1;
            *(uint4*)&Xs[nxt][row][half]     = pa0;
            *(uint4*)&Xs[nxt][row][half + 8] = pa1;
            *(uint4*)&Ws[nxt][row][half]     = pw0;
            *(uint4*)&Ws[nxt][row][half + 8] = pw1;
        }
        cur ^= 1;
    }

    float bias_j[4];
    const float* ebp = eb + e * H_DIM + h0 + wc;
#pragma unroll
    for (int j = 0; j < 4; ++j) bias_j[j] = ebp[j * 16 + l15];

#pragma unroll
    for (int i = 0; i < 4; ++i) {
#pragma unroll
        for (int r = 0; r < 4; ++r) {
            const int orow = wr + i * 16 + quad * 4 + r;
            if (i0 + orow < count) {
                const int tok = s_tok[orow];
                const float w = s_w[orow];
                float* op = out + (size_t)tok * H_DIM + h0 + wc + l15;
#pragma unroll
                for (int j = 0; j < 4; ++j) {
                    float v = w * (acc[i][j][r] + bias_j[j]);
                    if (ADD) v += op[j * 16];
                    op[j * 16] = v;
                }
            }
        }
    }
}

// ---------------- fallback GEMM (R10, fp32 staging — proven) ----------------
template <bool ADD>
__global__ __launch_bounds__(256) void moe_mfma_kernel(
    const float* __restrict__ x,
    const float* __restrict__ ew,
    const float* __restrict__ eb,
    const int* __restrict__ counts,
    const int2* __restrict__ entries,
    float* __restrict__ out)
{
    const int flat = blockIdx.x;
    const int lid  = (flat & 7) * 128 + (flat >> 3);
    const int h0 = (lid & 7) * 128;
    const int i0 = ((lid >> 3) & 7) * 128;
    const int e  = lid >> 6;

    int count = counts[e];
    if (count > CAP) count = CAP;
    if (i0 >= count) return;

    __shared__ unsigned short Xs[2][128][KPAD];
    __shared__ unsigned short Ws[2][128][KPAD];
    __shared__ int   s_tok[128];
    __shared__ float s_w[128];

    const int tid = threadIdx.x;
    if (tid < 128) {
        const int i = i0 + tid;
        if (i < count) {
            int2 en = entries[e * CAP + i];
            s_tok[tid] = en.x;
            s_w[tid] = __int_as_float(en.y);
        } else {
            s_tok[tid] = 0;
            s_w[tid] = 0.0f;
        }
    }
    __syncthreads();

    const int wave = tid >> 6;
    const int lane = tid & 63;
    const int wr = (wave >> 1) * 64;
    const int wc = (wave & 1) * 64;
    const int l15 = lane & 15;
    const int quad = lane >> 4;

    f32x4 acc[4][4] = {};

    const int a_kq = (tid & 7) * 4;
    const int a_r0 = tid >> 3;
    const int b_n  = tid & 127;
    const int b_dh = (tid >> 7) * 16;

    const float* ap[4];
#pragma unroll
    for (int it = 0; it < 4; ++it)
        ap[it] = x + (size_t)s_tok[a_r0 + it * 32] * D_DIM + a_kq;
    const float* bp = ew + (size_t)e * D_DIM * H_DIM
                    + (size_t)b_dh * H_DIM + h0 + b_n;

    float4 pa[4];
    float  pb[16];
#pragma unroll
    for (int it = 0; it < 4; ++it) pa[it] = *(const float4*)(ap[it]);
#pragma unroll
    for (int i = 0; i < 16; ++i)  pb[i] = bp[(size_t)i * H_DIM];

    {
#pragma unroll
        for (int it = 0; it < 4; ++it) {
            ushort4 p;
            p.x = f2bf(pa[it].x); p.y = f2bf(pa[it].y);
            p.z = f2bf(pa[it].z); p.w = f2bf(pa[it].w);
            *(ushort4*)&Xs[0][a_r0 + it * 32][a_kq] = p;
        }
        uint4 lo, hi;
        lo.x = pk2bf(pb[0], pb[1]);   lo.y = pk2bf(pb[2], pb[3]);
        lo.z = pk2bf(pb[4], pb[5]);   lo.w = pk2bf(pb[6], pb[7]);
        hi.x = pk2bf(pb[8], pb[9]);   hi.y = pk2bf(pb[10], pb[11]);
        hi.z = pk2bf(pb[12], pb[13]); hi.w = pk2bf(pb[14], pb[15]);
        *(uint4*)&Ws[0][b_n][b_dh]     = lo;
        *(uint4*)&Ws[0][b_n][b_dh + 8] = hi;
    }

    int cur = 0;
    for (int d0 = 0; d0 < D_DIM; d0 += 32) {
        __syncthreads();
        const bool more = (d0 + 32 < D_DIM);

        if (more) {
#pragma unroll
            for (int it = 0; it < 4; ++it)
                pa[it] = *(const float4*)(ap[it] + d0 + 32);
#pragma unroll
            for (int i = 0; i < 16; ++i)
                pb[i] = bp[(size_t)(d0 + 32 + i) * H_DIM];
        }

        bf16x8 af[4], bq[4];
#pragma unroll
        for (int i = 0; i < 4; ++i)
            af[i] = *(const bf16x8*)&Xs[cur][wr + i * 16 + l15][quad * 8];
#pragma unroll
        for (int j = 0; j < 4; ++j)
            bq[j] = *(const bf16x8*)&Ws[cur][wc + j * 16 + l15][quad * 8];
#pragma unroll
        for (int i = 0; i < 4; ++i)
#pragma unroll
            for (int j = 0; j < 4; ++j)
                acc[i][j] = __builtin_amdgcn_mfma_f32_16x16x32_bf16(
                    af[i], bq[j], acc[i][j], 0, 0, 0);

        if (more) {
            const int nxt = cur ^ 1;
#pragma unroll
            for (int it = 0; it < 4; ++it) {
                ushort4 p;
                p.x = f2bf(pa[it].x); p.y = f2bf(pa[it].y);
                p.z = f2bf(pa[it].z); p.w = f2bf(pa[it].w);
                *(ushort4*)&Xs[nxt][a_r0 + it * 32][a_kq] = p;
            }
            uint4 lo, hi;
            lo.x = pk2bf(pb[0], pb[1]);   lo.y = pk2bf(pb[2], pb[3]);
            lo.z = pk2bf(pb[4], pb[5]);   lo.w = pk2bf(pb[6], pb[7]);
            hi.x = pk2bf(pb[8], pb[9]);   hi.y = pk2bf(pb[10], pb[11]);
            hi.z = pk2bf(pb[12], pb[13]); hi.w = pk2bf(pb[14], pb[15]);
            *(uint4*)&Ws[nxt][b_n][b_dh]     = lo;
            *(uint4*)&Ws[nxt][b_n][b_dh + 8] = hi;
        }
        cur ^= 1;
    }

    float bias_j[4];
    const float* ebp = eb + e * H_DIM + h0 + wc;
#pragma unroll
    for (int j = 0; j < 4; ++j) bias_j[j] = ebp[j * 16 + l15];

#pragma unroll
    for (int i = 0; i < 4; ++i) {
#pragma unroll
        for (int r = 0; r < 4; ++r) {
            const int orow = wr + i * 16 + quad * 4 + r;
            if (i0 + orow < count) {
                const int tok = s_tok[orow];
                const float w = s_w[orow];
                float* op = out + (size_t)tok * H_DIM + h0 + wc + l15;
#pragma unroll
                for (int j = 0; j < 4; ++j) {
                    float v = w * (acc[i][j][r] + bias_j[j]);
                    if (ADD) v += op[j * 16];
                    op[j * 16] = v;
                }
            }
        }
    }
}

extern "C" void kernel_launch(void* const* d_in, const int* in_sizes, int n_in,
                              void* d_out, int out_size, void* d_ws, size_t ws_size,
                              hipStream_t stream)
{
    const float* x  = (const float*)d_in[0];
    const float* rw = (const float*)d_in[1];
    const float* rb = (const float*)d_in[2];
    const float* ew = (const float*)d_in[3];
    const float* eb = (const float*)d_in[4];

    char* ws = (char*)d_ws;
    int*  counts0  = (int*)ws;
    int*  counts1  = (int*)(ws + 64);
    int2* entries0 = (int2*)(ws + 1024);
    int2* entries1 = (int2*)(ws + 1024 + E_NUM * CAP * 8);

    // bf16 precache region (guarded by ws_size)
    const size_t XB_OFF = (size_t)1 << 20;                       // 1 MB
    const size_t XB_SZ  = (size_t)N_TOK * D_DIM * 2;             // 16 MB
    const size_t WT_OFF = XB_OFF + XB_SZ;
    const size_t WT_SZ  = (size_t)E_NUM * D_DIM * H_DIM * 2;     // 32 MB
    const bool precache = ws_size >= WT_OFF + WT_SZ;

    // res[] staged in d_out (128 KB of the 32 MB output buffer); pass A
    // later overwrites every token row.
    int4* res = (int4*)d_out;

    router_kernel<<<N_TOK / 8, 256, 0, stream>>>(x, rw, rb, res);

    build_lists<<<E_NUM, 256, 0, stream>>>(res, counts0, counts1,
                                           entries0, entries1);

    if (precache) {
        unsigned short* xbp = (unsigned short*)(ws + XB_OFF);
        unsigned short* wtp = (unsigned short*)(ws + WT_OFF);
        cvt_kernel<<<8192, 256, 0, stream>>>(x, ew, xbp, wtp);
        moe_gemm_bf16<false><<<1024, 256, 0, stream>>>(
            xbp, wtp, eb, counts0, entries0, (float*)d_out);
        moe_gemm_bf16<true><<<1024, 256, 0, stream>>>(
            xbp, wtp, eb, counts1, entries1, (float*)d_out);
    } else {
        moe_mfma_kernel<false><<<1024, 256, 0, stream>>>(
            x, ew, eb, counts0, entries0, (float*)d_out);
        moe_mfma_kernel<true><<<1024, 256, 0, stream>>>(
            x, ew, eb, counts1, entries1, (float*)d_out);
    }
}

// Round 7
// 277.222 us; speedup vs baseline: 1.5128x; 1.0292x over previous
//
#include <hip/hip_runtime.h>
#include <hip/hip_bf16.h>

// MoE block: N=8192, D=1024, H=1024, E=16, top-k=2. Inputs fp32, output fp32.
// out[n] = w1*(x@W_e1 + b_e1) + w2*(x@W_e2 + b_e2), w = top-2 of softmax.
//
// Round-12: XCD locality + cvt slimming. R11 counters: GEMM 52.9us/pass,
// FETCH 99MB (vs ~48 ideal) -- dense worklist lost the XCD swizzle, so the
// 8 h-blocks sharing an X tile land on different XCDs and each refetches it.
//   * moe_gemm_bf16: runtime-bijective m204 XCD swizzle over T active blocks
//     (T computed from counts in-kernel) -> contiguous loc chunk per XCD.
//   * router<WRITE_XB>: converts its own 2 token rows to bf16 xb[] (L1-hot
//     re-read, coalesced 32B/lane stores) -- removes X from cvt entirely.
//   * cvt_w_kernel: W-only transpose-convert (96MB traffic, ~20us).
//   * ws guard unchanged: <49MB falls back to proven fp32-staging path.
//   pass A (ADD=0): slot-0 lists -> out = w*(x@W+b)   (covers every token)
//   pass B (ADD=1): slot-1 lists -> out += w*(x@W+b)  (fp32 RMW, race-free)

#define N_TOK 8192
#define D_DIM 1024
#define H_DIM 1024
#define E_NUM 16
#define CAP   1024
#define KPAD  40    // LDS row stride in ushorts (80 B = 16B*5: b128-aligned)

typedef __attribute__((ext_vector_type(4))) float f32x4;
typedef __attribute__((ext_vector_type(8))) short bf16x8;

__device__ __forceinline__ unsigned short f2bf(float f) {
    unsigned int u = __float_as_uint(f);
    unsigned int r = u + 0x7fffu + ((u >> 16) & 1u);   // RNE
    return (unsigned short)(r >> 16);
}
__device__ __forceinline__ unsigned int pk2bf(float lo, float hi) {
    return (unsigned int)f2bf(lo) | ((unsigned int)f2bf(hi) << 16);
}

// ---------------- router (+ optional bf16 X side-product) ----------------
template <bool WRITE_XB>
__global__ __launch_bounds__(256, 4) void router_kernel(
    const float* __restrict__ x,
    const float* __restrict__ rw,
    const float* __restrict__ rb,
    int4* __restrict__ res,
    unsigned short* __restrict__ xb)
{
    const int wave = threadIdx.x >> 6;
    const int lane = threadIdx.x & 63;
    const int ds   = lane >> 4;
    const int e    = lane & 15;
    const int t0   = blockIdx.x * 8 + wave * 2;

    const float* x0  = x + (size_t)t0 * D_DIM + ds * 256;
    const float* x1  = x0 + D_DIM;
    const float* rwp = rw + ds * 4096 + e;

    double acc0 = 0.0, acc1 = 0.0;
#pragma unroll 2
    for (int g = 0; g < 8; ++g) {
        float s0 = 0.0f, s1 = 0.0f;
#pragma unroll
        for (int u = 0; u < 8; ++u) {
            const int jb = g * 8 + u;
            const float4 a = *(const float4*)(x0 + jb * 4);
            const float4 b = *(const float4*)(x1 + jb * 4);
            const float w0 = rwp[jb * 64];
            const float w1 = rwp[jb * 64 + 16];
            const float w2 = rwp[jb * 64 + 32];
            const float w3 = rwp[jb * 64 + 48];
            s0 = fmaf(a.w, w3, fmaf(a.z, w2, fmaf(a.y, w1, fmaf(a.x, w0, s0))));
            s1 = fmaf(b.w, w3, fmaf(b.z, w2, fmaf(b.y, w1, fmaf(b.x, w0, s1))));
        }
        acc0 += (double)s0;
        acc1 += (double)s1;
    }

    // bf16 X side-product: each lane re-reads its own 16 floats per row
    // (L1-hot, lane-distinct, coalesced) and stores 32B of bf16.
    if (WRITE_XB) {
#pragma unroll
        for (int t = 0; t < 2; ++t) {
            const float* src = x + (size_t)(t0 + t) * D_DIM + lane * 16;
            unsigned short* dst = xb + (size_t)(t0 + t) * D_DIM + lane * 16;
            const float4 v0 = *(const float4*)(src);
            const float4 v1 = *(const float4*)(src + 4);
            const float4 v2 = *(const float4*)(src + 8);
            const float4 v3 = *(const float4*)(src + 12);
            uint4 lo, hi;
            lo.x = pk2bf(v0.x, v0.y); lo.y = pk2bf(v0.z, v0.w);
            lo.z = pk2bf(v1.x, v1.y); lo.w = pk2bf(v1.z, v1.w);
            hi.x = pk2bf(v2.x, v2.y); hi.y = pk2bf(v2.z, v2.w);
            hi.z = pk2bf(v3.x, v3.y); hi.w = pk2bf(v3.z, v3.w);
            *(uint4*)dst       = lo;
            *(uint4*)(dst + 8) = hi;
        }
    }

    double v0 = acc0, v1 = acc1;
    v0 += __shfl_xor(v0, 16); v0 += __shfl_xor(v0, 32);
    v1 += __shfl_xor(v1, 16); v1 += __shfl_xor(v1, 32);

    __shared__ double lg[4][2][E_NUM];
    if (ds == 0) {
        const double bias = (double)rb[e];
        lg[wave][0][e] = v0 + bias;
        lg[wave][1][e] = v1 + bias;
    }
    __syncthreads();

    if (lane < 2) {
        const double* L = lg[wave][lane];
        double m = L[0];
#pragma unroll
        for (int k = 1; k < E_NUM; ++k) m = fmax(m, L[k]);

        int e1 = 0;
#pragma unroll
        for (int k = 1; k < E_NUM; ++k) if (L[k] > L[e1]) e1 = k;
        int e2 = (e1 == 0) ? 1 : 0;
        for (int k = 0; k < E_NUM; ++k)
            if (k != e1 && L[k] > L[e2]) e2 = k;

        float s = 0.0f;
#pragma unroll
        for (int k = 0; k < E_NUM; ++k) s = fmaf(expf((float)(L[k] - m)), 1.0f, s);
        const float w1 = expf((float)(L[e1] - m)) / s;
        const float w2 = expf((float)(L[e2] - m)) / s;

        const int n = t0 + lane;
        res[n] = make_int4(e1, e2, __float_as_int(w1), __float_as_int(w2));
    }
}

// ---------------- build_lists (unchanged) ----------------
__global__ __launch_bounds__(256) void build_lists(
    const int4* __restrict__ res,
    int* __restrict__ counts0, int* __restrict__ counts1,
    int2* __restrict__ entries0, int2* __restrict__ entries1)
{
    const int e = blockIdx.x;
    __shared__ int c0, c1;
    if (threadIdx.x == 0) { c0 = 0; c1 = 0; }
    __syncthreads();

    for (int i = threadIdx.x; i < N_TOK; i += 256) {
        const int4 r = res[i];
        if (r.x == e) {
            int p = atomicAdd(&c0, 1);
            if (p < CAP) entries0[e * CAP + p] = make_int2(i, r.z);
        }
        if (r.y == e) {
            int p = atomicAdd(&c1, 1);
            if (p < CAP) entries1[e * CAP + p] = make_int2(i, r.w);
        }
    }
    __syncthreads();
    if (threadIdx.x == 0) { counts0[e] = c0; counts1[e] = c1; }
}

// ---------------- cvt: Wt = bf16(W) transposed [E][H][D] ----------------
__global__ __launch_bounds__(256) void cvt_w_kernel(
    const float* __restrict__ ew,
    unsigned short* __restrict__ wt)
{
    const int tid = threadIdx.x;
    __shared__ unsigned short Ts[64][68];
    const int wi = blockIdx.x;                // 0..4095
    const int e  = wi >> 8;                   // 256 tiles/expert
    const int kt = (wi >> 4) & 15;
    const int ht = wi & 15;

    // read: 64 k-rows x 64 h, coalesced float4, convert, store [k][h]
    {
        const int kl0 = tid >> 4;             // 0..15 (+16*i)
        const int hl  = (tid & 15) * 4;
        const float* src = ew + (size_t)e * (D_DIM * H_DIM)
                         + (size_t)(kt * 64 + kl0) * H_DIM + ht * 64 + hl;
#pragma unroll
        for (int i = 0; i < 4; ++i) {
            const float4 v = *(const float4*)(src + (size_t)i * 16 * H_DIM);
            ushort4 p;
            p.x = f2bf(v.x); p.y = f2bf(v.y); p.z = f2bf(v.z); p.w = f2bf(v.w);
            *(ushort4*)&Ts[kl0 + i * 16][hl] = p;
        }
    }
    __syncthreads();
    // write: 64 h-rows x 64 k, transposed gather from LDS, 32B/thread
    {
        const int h2 = tid >> 2;              // 0..63
        const int kc = (tid & 3) * 16;
        unsigned int r[8];
#pragma unroll
        for (int i = 0; i < 8; ++i)
            r[i] = (unsigned int)Ts[kc + 2 * i][h2]
                 | ((unsigned int)Ts[kc + 2 * i + 1][h2] << 16);
        unsigned short* dst = wt + (size_t)e * (D_DIM * H_DIM)
                            + (size_t)(ht * 64 + h2) * D_DIM + kt * 64 + kc;
        *(uint4*)dst       = *(uint4*)&r[0];
        *(uint4*)(dst + 8) = *(uint4*)&r[4];
    }
}

// ---------------- GEMM: bf16 precache, dense worklist + XCD swizzle ----------------
template <bool ADD>
__global__ __launch_bounds__(256) void moe_gemm_bf16(
    const unsigned short* __restrict__ xb,   // [N][D] bf16
    const unsigned short* __restrict__ wt,   // [E][H][D] bf16
    const float* __restrict__ eb,
    const int* __restrict__ counts,
    const int2* __restrict__ entries,
    float* __restrict__ out)
{
    // total active blocks T (uniform across blocks, from counts)
    int T = 0;
    for (int k = 0; k < E_NUM; ++k) {
        int c = counts[k]; if (c > CAP) c = CAP;
        T += ((c + 127) >> 7) << 3;            // ceil(c/128) * 8 h-blocks
    }
    if ((int)blockIdx.x >= T) return;

    // m204 bijective XCD swizzle over [0,T): b=8k+xcd -> contiguous loc
    // chunk per XCD, so the 8 h-blocks sharing an X tile stay on one XCD.
    const int q = T >> 3, r = T & 7;
    const int xcd = blockIdx.x & 7;
    int loc = (xcd < r ? xcd * (q + 1) : r * (q + 1) + (xcd - r) * q)
            + (blockIdx.x >> 3);

    // walk: loc -> (e, i-chunk, h)
    int e = 0, count = 0;
    for (; e < E_NUM; ++e) {
        int c = counts[e]; if (c > CAP) c = CAP;
        const int nb = ((c + 127) >> 7) << 3;
        if (loc < nb) { count = c; break; }
        loc -= nb;
    }
    const int i0 = (loc >> 3) * 128;
    const int h0 = (loc & 7) * 128;

    __shared__ unsigned short Xs[2][128][KPAD];
    __shared__ unsigned short Ws[2][128][KPAD];
    __shared__ int   s_tok[128];
    __shared__ float s_w[128];

    const int tid = threadIdx.x;
    if (tid < 128) {
        const int i = i0 + tid;
        if (i < count) {
            int2 en = entries[e * CAP + i];
            s_tok[tid] = en.x;
            s_w[tid] = __int_as_float(en.y);
        } else {
            s_tok[tid] = 0;
            s_w[tid] = 0.0f;
        }
    }
    __syncthreads();

    const int wave = tid >> 6;
    const int lane = tid & 63;
    const int wr = (wave >> 1) * 64;
    const int wc = (wave & 1) * 64;
    const int l15 = lane & 15;
    const int quad = lane >> 4;

    f32x4 acc[4][4] = {};

    // staging map: thread -> (row 0..127, 16-ushort half)
    const int row  = tid >> 1;
    const int half = (tid & 1) * 16;
    const unsigned short* xp = xb + (size_t)s_tok[row] * D_DIM + half;
    const unsigned short* wp = wt + (size_t)(e * H_DIM + h0 + row) * D_DIM + half;

    // prefetch tile 0 -> regs -> buf 0
    uint4 pa0 = *(const uint4*)(xp);
    uint4 pa1 = *(const uint4*)(xp + 8);
    uint4 pw0 = *(const uint4*)(wp);
    uint4 pw1 = *(const uint4*)(wp + 8);
    *(uint4*)&Xs[0][row][half]     = pa0;
    *(uint4*)&Xs[0][row][half + 8] = pa1;
    *(uint4*)&Ws[0][row][half]     = pw0;
    *(uint4*)&Ws[0][row][half + 8] = pw1;

    int cur = 0;
    for (int d0 = 0; d0 < D_DIM; d0 += 32) {
        __syncthreads();                       // buf[cur] ready
        const bool more = (d0 + 32 < D_DIM);

        if (more) {                            // issue next-tile loads
            pa0 = *(const uint4*)(xp + d0 + 32);
            pa1 = *(const uint4*)(xp + d0 + 40);
            pw0 = *(const uint4*)(wp + d0 + 32);
            pw1 = *(const uint4*)(wp + d0 + 40);
        }

        bf16x8 af[4], bq[4];
#pragma unroll
        for (int i = 0; i < 4; ++i)
            af[i] = *(const bf16x8*)&Xs[cur][wr + i * 16 + l15][quad * 8];
#pragma unroll
        for (int j = 0; j < 4; ++j)
            bq[j] = *(const bf16x8*)&Ws[cur][wc + j * 16 + l15][quad * 8];
#pragma unroll
        for (int i = 0; i < 4; ++i)
#pragma unroll
            for (int j = 0; j < 4; ++j)
                acc[i][j] = __builtin_amdgcn_mfma_f32_16x16x32_bf16(
                    af[i], bq[j], acc[i][j], 0, 0, 0);

        if (more) {                            // write next tile
            const int nxt = cur ^ 1;
            *(uint4*)&Xs[nxt][row][half]     = pa0;
            *(uint4*)&Xs[nxt][row][half + 8] = pa1;
            *(uint4*)&Ws[nxt][row][half]     = pw0;
            *(uint4*)&Ws[nxt][row][half + 8] = pw1;
        }
        cur ^= 1;
    }

    float bias_j[4];
    const float* ebp = eb + e * H_DIM + h0 + wc;
#pragma unroll
    for (int j = 0; j < 4; ++j) bias_j[j] = ebp[j * 16 + l15];

#pragma unroll
    for (int i = 0; i < 4; ++i) {
#pragma unroll
        for (int r2 = 0; r2 < 4; ++r2) {
            const int orow = wr + i * 16 + quad * 4 + r2;
            if (i0 + orow < count) {
                const int tok = s_tok[orow];
                const float w = s_w[orow];
                float* op = out + (size_t)tok * H_DIM + h0 + wc + l15;
#pragma unroll
                for (int j = 0; j < 4; ++j) {
                    float v = w * (acc[i][j][r2] + bias_j[j]);
                    if (ADD) v += op[j * 16];
                    op[j * 16] = v;
                }
            }
        }
    }
}

// ---------------- fallback GEMM (fp32 staging — proven) ----------------
template <bool ADD>
__global__ __launch_bounds__(256) void moe_mfma_kernel(
    const float* __restrict__ x,
    const float* __restrict__ ew,
    const float* __restrict__ eb,
    const int* __restrict__ counts,
    const int2* __restrict__ entries,
    float* __restrict__ out)
{
    const int flat = blockIdx.x;
    const int lid  = (flat & 7) * 128 + (flat >> 3);
    const int h0 = (lid & 7) * 128;
    const int i0 = ((lid >> 3) & 7) * 128;
    const int e  = lid >> 6;

    int count = counts[e];
    if (count > CAP) count = CAP;
    if (i0 >= count) return;

    __shared__ unsigned short Xs[2][128][KPAD];
    __shared__ unsigned short Ws[2][128][KPAD];
    __shared__ int   s_tok[128];
    __shared__ float s_w[128];

    const int tid = threadIdx.x;
    if (tid < 128) {
        const int i = i0 + tid;
        if (i < count) {
            int2 en = entries[e * CAP + i];
            s_tok[tid] = en.x;
            s_w[tid] = __int_as_float(en.y);
        } else {
            s_tok[tid] = 0;
            s_w[tid] = 0.0f;
        }
    }
    __syncthreads();

    const int wave = tid >> 6;
    const int lane = tid & 63;
    const int wr = (wave >> 1) * 64;
    const int wc = (wave & 1) * 64;
    const int l15 = lane & 15;
    const int quad = lane >> 4;

    f32x4 acc[4][4] = {};

    const int a_kq = (tid & 7) * 4;
    const int a_r0 = tid >> 3;
    const int b_n  = tid & 127;
    const int b_dh = (tid >> 7) * 16;

    const float* ap[4];
#pragma unroll
    for (int it = 0; it < 4; ++it)
        ap[it] = x + (size_t)s_tok[a_r0 + it * 32] * D_DIM + a_kq;
    const float* bp = ew + (size_t)e * D_DIM * H_DIM
                    + (size_t)b_dh * H_DIM + h0 + b_n;

    float4 pa[4];
    float  pb[16];
#pragma unroll
    for (int it = 0; it < 4; ++it) pa[it] = *(const float4*)(ap[it]);
#pragma unroll
    for (int i = 0; i < 16; ++i)  pb[i] = bp[(size_t)i * H_DIM];

    {
#pragma unroll
        for (int it = 0; it < 4; ++it) {
            ushort4 p;
            p.x = f2bf(pa[it].x); p.y = f2bf(pa[it].y);
            p.z = f2bf(pa[it].z); p.w = f2bf(pa[it].w);
            *(ushort4*)&Xs[0][a_r0 + it * 32][a_kq] = p;
        }
        uint4 lo, hi;
        lo.x = pk2bf(pb[0], pb[1]);   lo.y = pk2bf(pb[2], pb[3]);
        lo.z = pk2bf(pb[4], pb[5]);   lo.w = pk2bf(pb[6], pb[7]);
        hi.x = pk2bf(pb[8], pb[9]);   hi.y = pk2bf(pb[10], pb[11]);
        hi.z = pk2bf(pb[12], pb[13]); hi.w = pk2bf(pb[14], pb[15]);
        *(uint4*)&Ws[0][b_n][b_dh]     = lo;
        *(uint4*)&Ws[0][b_n][b_dh + 8] = hi;
    }

    int cur = 0;
    for (int d0 = 0; d0 < D_DIM; d0 += 32) {
        __syncthreads();
        const bool more = (d0 + 32 < D_DIM);

        if (more) {
#pragma unroll
            for (int it = 0; it < 4; ++it)
                pa[it] = *(const float4*)(ap[it] + d0 + 32);
#pragma unroll
            for (int i = 0; i < 16; ++i)
                pb[i] = bp[(size_t)(d0 + 32 + i) * H_DIM];
        }

        bf16x8 af[4], bq[4];
#pragma unroll
        for (int i = 0; i < 4; ++i)
            af[i] = *(const bf16x8*)&Xs[cur][wr + i * 16 + l15][quad * 8];
#pragma unroll
        for (int j = 0; j < 4; ++j)
            bq[j] = *(const bf16x8*)&Ws[cur][wc + j * 16 + l15][quad * 8];
#pragma unroll
        for (int i = 0; i < 4; ++i)
#pragma unroll
            for (int j = 0; j < 4; ++j)
                acc[i][j] = __builtin_amdgcn_mfma_f32_16x16x32_bf16(
                    af[i], bq[j], acc[i][j], 0, 0, 0);

        if (more) {
            const int nxt = cur ^ 1;
#pragma unroll
            for (int it = 0; it < 4; ++it) {
                ushort4 p;
                p.x = f2bf(pa[it].x); p.y = f2bf(pa[it].y);
                p.z = f2bf(pa[it].z); p.w = f2bf(pa[it].w);
                *(ushort4*)&Xs[nxt][a_r0 + it * 32][a_kq] = p;
            }
            uint4 lo, hi;
            lo.x = pk2bf(pb[0], pb[1]);   lo.y = pk2bf(pb[2], pb[3]);
            lo.z = pk2bf(pb[4], pb[5]);   lo.w = pk2bf(pb[6], pb[7]);
            hi.x = pk2bf(pb[8], pb[9]);   hi.y = pk2bf(pb[10], pb[11]);
            hi.z = pk2bf(pb[12], pb[13]); hi.w = pk2bf(pb[14], pb[15]);
            *(uint4*)&Ws[nxt][b_n][b_dh]     = lo;
            *(uint4*)&Ws[nxt][b_n][b_dh + 8] = hi;
        }
        cur ^= 1;
    }

    float bias_j[4];
    const float* ebp = eb + e * H_DIM + h0 + wc;
#pragma unroll
    for (int j = 0; j < 4; ++j) bias_j[j] = ebp[j * 16 + l15];

#pragma unroll
    for (int i = 0; i < 4; ++i) {
#pragma unroll
        for (int r2 = 0; r2 < 4; ++r2) {
            const int orow = wr + i * 16 + quad * 4 + r2;
            if (i0 + orow < count) {
                const int tok = s_tok[orow];
                const float w = s_w[orow];
                float* op = out + (size_t)tok * H_DIM + h0 + wc + l15;
#pragma unroll
                for (int j = 0; j < 4; ++j) {
                    float v = w * (acc[i][j][r2] + bias_j[j]);
                    if (ADD) v += op[j * 16];
                    op[j * 16] = v;
                }
            }
        }
    }
}

extern "C" void kernel_launch(void* const* d_in, const int* in_sizes, int n_in,
                              void* d_out, int out_size, void* d_ws, size_t ws_size,
                              hipStream_t stream)
{
    const float* x  = (const float*)d_in[0];
    const float* rw = (const float*)d_in[1];
    const float* rb = (const float*)d_in[2];
    const float* ew = (const float*)d_in[3];
    const float* eb = (const float*)d_in[4];

    char* ws = (char*)d_ws;
    int*  counts0  = (int*)ws;
    int*  counts1  = (int*)(ws + 64);
    int2* entries0 = (int2*)(ws + 1024);
    int2* entries1 = (int2*)(ws + 1024 + E_NUM * CAP * 8);

    // bf16 precache region (guarded by ws_size)
    const size_t XB_OFF = (size_t)1 << 20;                       // 1 MB
    const size_t XB_SZ  = (size_t)N_TOK * D_DIM * 2;             // 16 MB
    const size_t WT_OFF = XB_OFF + XB_SZ;
    const size_t WT_SZ  = (size_t)E_NUM * D_DIM * H_DIM * 2;     // 32 MB
    const bool precache = ws_size >= WT_OFF + WT_SZ;

    // res[] staged in d_out (128 KB of the 32 MB output buffer); pass A
    // later overwrites every token row.
    int4* res = (int4*)d_out;

    if (precache) {
        unsigned short* xbp = (unsigned short*)(ws + XB_OFF);
        unsigned short* wtp = (unsigned short*)(ws + WT_OFF);
        router_kernel<true><<<N_TOK / 8, 256, 0, stream>>>(x, rw, rb, res, xbp);
        build_lists<<<E_NUM, 256, 0, stream>>>(res, counts0, counts1,
                                               entries0, entries1);
        cvt_w_kernel<<<4096, 256, 0, stream>>>(ew, wtp);
        moe_gemm_bf16<false><<<1024, 256, 0, stream>>>(
            xbp, wtp, eb, counts0, entries0, (float*)d_out);
        moe_gemm_bf16<true><<<1024, 256, 0, stream>>>(
            xbp, wtp, eb, counts1, entries1, (float*)d_out);
    } else {
        router_kernel<false><<<N_TOK / 8, 256, 0, stream>>>(x, rw, rb, res, nullptr);
        build_lists<<<E_NUM, 256, 0, stream>>>(res, counts0, counts1,
                                               entries0, entries1);
        moe_mfma_kernel<false><<<1024, 256, 0, stream>>>(
            x, ew, eb, counts0, entries0, (float*)d_out);
        moe_mfma_kernel<true><<<1024, 256, 0, stream>>>(
            x, ew, eb, counts1, entries1, (float*)d_out);
    }
}

// Round 10
// 276.770 us; speedup vs baseline: 1.5152x; 1.0016x over previous
//
#include <hip/hip_runtime.h>
#include <hip/hip_bf16.h>

// MoE block: N=8192, D=1024, H=1024, E=16, top-k=2. Inputs fp32, output fp32.
// out[n] = w1*(x@W_e1 + b_e1) + w2*(x@W_e2 + b_e2), w = top-2 of softmax.
//
// Round-15: REVERT to the proven round-12 configuration (277.2us, passed).
// fused_prep (R13/R14) failed the container 2-for-2 on identical source --
// per the R9->R10 precedent that implicates the kernel, not infra. The
// fusion gamble is abandoned; this re-establishes the best verified state.
//   * router<WRITE_XB>: GEMV + top-2, writes res[] + bf16 xb[] side-product
//   * build_lists: per-expert compaction via LDS atomics
//   * cvt_w_kernel: W transpose-convert -> wt[E][H][D] bf16
//   * moe_gemm_bf16: dense worklist + bijective XCD swizzle, bf16 staging,
//     double-buffered LDS, reg prefetch, 1 barrier/K-step
//   * ws guard: <49MB falls back to fp32-staging moe_mfma_kernel path
//   pass A (ADD=0): slot-0 lists -> out = w*(x@W+b)   (covers every token)
//   pass B (ADD=1): slot-1 lists -> out += w*(x@W+b)  (fp32 RMW, race-free)

#define N_TOK 8192
#define D_DIM 1024
#define H_DIM 1024
#define E_NUM 16
#define CAP   1024
#define KPAD  40    // LDS row stride in ushorts (80 B = 16B*5: b128-aligned)

typedef __attribute__((ext_vector_type(4))) float f32x4;
typedef __attribute__((ext_vector_type(8))) short bf16x8;

__device__ __forceinline__ unsigned short f2bf(float f) {
    unsigned int u = __float_as_uint(f);
    unsigned int r = u + 0x7fffu + ((u >> 16) & 1u);   // RNE
    return (unsigned short)(r >> 16);
}
__device__ __forceinline__ unsigned int pk2bf(float lo, float hi) {
    return (unsigned int)f2bf(lo) | ((unsigned int)f2bf(hi) << 16);
}

// ---------------- router (+ optional bf16 X side-product) ----------------
template <bool WRITE_XB>
__global__ __launch_bounds__(256, 4) void router_kernel(
    const float* __restrict__ x,
    const float* __restrict__ rw,
    const float* __restrict__ rb,
    int4* __restrict__ res,
    unsigned short* __restrict__ xb)
{
    const int wave = threadIdx.x >> 6;
    const int lane = threadIdx.x & 63;
    const int ds   = lane >> 4;
    const int e    = lane & 15;
    const int t0   = blockIdx.x * 8 + wave * 2;

    const float* x0  = x + (size_t)t0 * D_DIM + ds * 256;
    const float* x1  = x0 + D_DIM;
    const float* rwp = rw + ds * 4096 + e;

    double acc0 = 0.0, acc1 = 0.0;
#pragma unroll 2
    for (int g = 0; g < 8; ++g) {
        float s0 = 0.0f, s1 = 0.0f;
#pragma unroll
        for (int u = 0; u < 8; ++u) {
            const int jb = g * 8 + u;
            const float4 a = *(const float4*)(x0 + jb * 4);
            const float4 b = *(const float4*)(x1 + jb * 4);
            const float w0 = rwp[jb * 64];
            const float w1 = rwp[jb * 64 + 16];
            const float w2 = rwp[jb * 64 + 32];
            const float w3 = rwp[jb * 64 + 48];
            s0 = fmaf(a.w, w3, fmaf(a.z, w2, fmaf(a.y, w1, fmaf(a.x, w0, s0))));
            s1 = fmaf(b.w, w3, fmaf(b.z, w2, fmaf(b.y, w1, fmaf(b.x, w0, s1))));
        }
        acc0 += (double)s0;
        acc1 += (double)s1;
    }

    // bf16 X side-product: each lane re-reads its own 16 floats per row
    // (L1-hot, lane-distinct, coalesced) and stores 32B of bf16.
    if (WRITE_XB) {
#pragma unroll
        for (int t = 0; t < 2; ++t) {
            const float* src = x + (size_t)(t0 + t) * D_DIM + lane * 16;
            unsigned short* dst = xb + (size_t)(t0 + t) * D_DIM + lane * 16;
            const float4 v0 = *(const float4*)(src);
            const float4 v1 = *(const float4*)(src + 4);
            const float4 v2 = *(const float4*)(src + 8);
            const float4 v3 = *(const float4*)(src + 12);
            uint4 lo, hi;
            lo.x = pk2bf(v0.x, v0.y); lo.y = pk2bf(v0.z, v0.w);
            lo.z = pk2bf(v1.x, v1.y); lo.w = pk2bf(v1.z, v1.w);
            hi.x = pk2bf(v2.x, v2.y); hi.y = pk2bf(v2.z, v2.w);
            hi.z = pk2bf(v3.x, v3.y); hi.w = pk2bf(v3.z, v3.w);
            *(uint4*)dst       = lo;
            *(uint4*)(dst + 8) = hi;
        }
    }

    double v0 = acc0, v1 = acc1;
    v0 += __shfl_xor(v0, 16); v0 += __shfl_xor(v0, 32);
    v1 += __shfl_xor(v1, 16); v1 += __shfl_xor(v1, 32);

    __shared__ double lg[4][2][E_NUM];
    if (ds == 0) {
        const double bias = (double)rb[e];
        lg[wave][0][e] = v0 + bias;
        lg[wave][1][e] = v1 + bias;
    }
    __syncthreads();

    if (lane < 2) {
        const double* L = lg[wave][lane];
        double m = L[0];
#pragma unroll
        for (int k = 1; k < E_NUM; ++k) m = fmax(m, L[k]);

        int e1 = 0;
#pragma unroll
        for (int k = 1; k < E_NUM; ++k) if (L[k] > L[e1]) e1 = k;
        int e2 = (e1 == 0) ? 1 : 0;
        for (int k = 0; k < E_NUM; ++k)
            if (k != e1 && L[k] > L[e2]) e2 = k;

        float s = 0.0f;
#pragma unroll
        for (int k = 0; k < E_NUM; ++k) s = fmaf(expf((float)(L[k] - m)), 1.0f, s);
        const float w1 = expf((float)(L[e1] - m)) / s;
        const float w2 = expf((float)(L[e2] - m)) / s;

        const int n = t0 + lane;
        res[n] = make_int4(e1, e2, __float_as_int(w1), __float_as_int(w2));
    }
}

// ---------------- build_lists (unchanged) ----------------
__global__ __launch_bounds__(256) void build_lists(
    const int4* __restrict__ res,
    int* __restrict__ counts0, int* __restrict__ counts1,
    int2* __restrict__ entries0, int2* __restrict__ entries1)
{
    const int e = blockIdx.x;
    __shared__ int c0, c1;
    if (threadIdx.x == 0) { c0 = 0; c1 = 0; }
    __syncthreads();

    for (int i = threadIdx.x; i < N_TOK; i += 256) {
        const int4 r = res[i];
        if (r.x == e) {
            int p = atomicAdd(&c0, 1);
            if (p < CAP) entries0[e * CAP + p] = make_int2(i, r.z);
        }
        if (r.y == e) {
            int p = atomicAdd(&c1, 1);
            if (p < CAP) entries1[e * CAP + p] = make_int2(i, r.w);
        }
    }
    __syncthreads();
    if (threadIdx.x == 0) { counts0[e] = c0; counts1[e] = c1; }
}

// ---------------- cvt: Wt = bf16(W) transposed [E][H][D] ----------------
__global__ __launch_bounds__(256) void cvt_w_kernel(
    const float* __restrict__ ew,
    unsigned short* __restrict__ wt)
{
    const int tid = threadIdx.x;
    __shared__ unsigned short Ts[64][68];
    const int wi = blockIdx.x;                // 0..4095
    const int e  = wi >> 8;                   // 256 tiles/expert
    const int kt = (wi >> 4) & 15;
    const int ht = wi & 15;

    // read: 64 k-rows x 64 h, coalesced float4, convert, store [k][h]
    {
        const int kl0 = tid >> 4;             // 0..15 (+16*i)
        const int hl  = (tid & 15) * 4;
        const float* src = ew + (size_t)e * (D_DIM * H_DIM)
                         + (size_t)(kt * 64 + kl0) * H_DIM + ht * 64 + hl;
#pragma unroll
        for (int i = 0; i < 4; ++i) {
            const float4 v = *(const float4*)(src + (size_t)i * 16 * H_DIM);
            ushort4 p;
            p.x = f2bf(v.x); p.y = f2bf(v.y); p.z = f2bf(v.z); p.w = f2bf(v.w);
            *(ushort4*)&Ts[kl0 + i * 16][hl] = p;
        }
    }
    __syncthreads();
    // write: 64 h-rows x 64 k, transposed gather from LDS, 32B/thread
    {
        const int h2 = tid >> 2;              // 0..63
        const int kc = (tid & 3) * 16;
        unsigned int r[8];
#pragma unroll
        for (int i = 0; i < 8; ++i)
            r[i] = (unsigned int)Ts[kc + 2 * i][h2]
                 | ((unsigned int)Ts[kc + 2 * i + 1][h2] << 16);
        unsigned short* dst = wt + (size_t)e * (D_DIM * H_DIM)
                            + (size_t)(ht * 64 + h2) * D_DIM + kt * 64 + kc;
        *(uint4*)dst       = *(uint4*)&r[0];
        *(uint4*)(dst + 8) = *(uint4*)&r[4];
    }
}

// ---------------- GEMM: bf16 precache, dense worklist + XCD swizzle ----------------
template <bool ADD>
__global__ __launch_bounds__(256) void moe_gemm_bf16(
    const unsigned short* __restrict__ xb,   // [N][D] bf16
    const unsigned short* __restrict__ wt,   // [E][H][D] bf16
    const float* __restrict__ eb,
    const int* __restrict__ counts,
    const int2* __restrict__ entries,
    float* __restrict__ out)
{
    // total active blocks T (uniform across blocks, from counts)
    int T = 0;
    for (int k = 0; k < E_NUM; ++k) {
        int c = counts[k]; if (c > CAP) c = CAP;
        T += ((c + 127) >> 7) << 3;            // ceil(c/128) * 8 h-blocks
    }
    if ((int)blockIdx.x >= T) return;

    // m204 bijective XCD swizzle over [0,T): b=8k+xcd -> contiguous loc
    // chunk per XCD, so the 8 h-blocks sharing an X tile stay on one XCD.
    const int q = T >> 3, r = T & 7;
    const int xcd = blockIdx.x & 7;
    int loc = (xcd < r ? xcd * (q + 1) : r * (q + 1) + (xcd - r) * q)
            + (blockIdx.x >> 3);

    // walk: loc -> (e, i-chunk, h)
    int e = 0, count = 0;
    for (; e < E_NUM; ++e) {
        int c = counts[e]; if (c > CAP) c = CAP;
        const int nb = ((c + 127) >> 7) << 3;
        if (loc < nb) { count = c; break; }
        loc -= nb;
    }
    const int i0 = (loc >> 3) * 128;
    const int h0 = (loc & 7) * 128;

    __shared__ unsigned short Xs[2][128][KPAD];
    __shared__ unsigned short Ws[2][128][KPAD];
    __shared__ int   s_tok[128];
    __shared__ float s_w[128];

    const int tid = threadIdx.x;
    if (tid < 128) {
        const int i = i0 + tid;
        if (i < count) {
            int2 en = entries[e * CAP + i];
            s_tok[tid] = en.x;
            s_w[tid] = __int_as_float(en.y);
        } else {
            s_tok[tid] = 0;
            s_w[tid] = 0.0f;
        }
    }
    __syncthreads();

    const int wave = tid >> 6;
    const int lane = tid & 63;
    const int wr = (wave >> 1) * 64;
    const int wc = (wave & 1) * 64;
    const int l15 = lane & 15;
    const int quad = lane >> 4;

    f32x4 acc[4][4] = {};

    // staging map: thread -> (row 0..127, 16-ushort half)
    const int row  = tid >> 1;
    const int half = (tid & 1) * 16;
    const unsigned short* xp = xb + (size_t)s_tok[row] * D_DIM + half;
    const unsigned short* wp = wt + (size_t)(e * H_DIM + h0 + row) * D_DIM + half;

    // prefetch tile 0 -> regs -> buf 0
    uint4 pa0 = *(const uint4*)(xp);
    uint4 pa1 = *(const uint4*)(xp + 8);
    uint4 pw0 = *(const uint4*)(wp);
    uint4 pw1 = *(const uint4*)(wp + 8);
    *(uint4*)&Xs[0][row][half]     = pa0;
    *(uint4*)&Xs[0][row][half + 8] = pa1;
    *(uint4*)&Ws[0][row][half]     = pw0;
    *(uint4*)&Ws[0][row][half + 8] = pw1;

    int cur = 0;
    for (int d0 = 0; d0 < D_DIM; d0 += 32) {
        __syncthreads();                       // buf[cur] ready
        const bool more = (d0 + 32 < D_DIM);

        if (more) {                            // issue next-tile loads
            pa0 = *(const uint4*)(xp + d0 + 32);
            pa1 = *(const uint4*)(xp + d0 + 40);
            pw0 = *(const uint4*)(wp + d0 + 32);
            pw1 = *(const uint4*)(wp + d0 + 40);
        }

        bf16x8 af[4], bq[4];
#pragma unroll
        for (int i = 0; i < 4; ++i)
            af[i] = *(const bf16x8*)&Xs[cur][wr + i * 16 + l15][quad * 8];
#pragma unroll
        for (int j = 0; j < 4; ++j)
            bq[j] = *(const bf16x8*)&Ws[cur][wc + j * 16 + l15][quad * 8];
#pragma unroll
        for (int i = 0; i < 4; ++i)
#pragma unroll
            for (int j = 0; j < 4; ++j)
                acc[i][j] = __builtin_amdgcn_mfma_f32_16x16x32_bf16(
                    af[i], bq[j], acc[i][j], 0, 0, 0);

        if (more) {                            // write next tile
            const int nxt = cur ^ 1;
            *(uint4*)&Xs[nxt][row][half]     = pa0;
            *(uint4*)&Xs[nxt][row][half + 8] = pa1;
            *(uint4*)&Ws[nxt][row][half]     = pw0;
            *(uint4*)&Ws[nxt][row][half + 8] = pw1;
        }
        cur ^= 1;
    }

    float bias_j[4];
    const float* ebp = eb + e * H_DIM + h0 + wc;
#pragma unroll
    for (int j = 0; j < 4; ++j) bias_j[j] = ebp[j * 16 + l15];

#pragma unroll
    for (int i = 0; i < 4; ++i) {
#pragma unroll
        for (int r2 = 0; r2 < 4; ++r2) {
            const int orow = wr + i * 16 + quad * 4 + r2;
            if (i0 + orow < count) {
                const int tok = s_tok[orow];
                const float w = s_w[orow];
                float* op = out + (size_t)tok * H_DIM + h0 + wc + l15;
#pragma unroll
                for (int j = 0; j < 4; ++j) {
                    float v = w * (acc[i][j][r2] + bias_j[j]);
                    if (ADD) v += op[j * 16];
                    op[j * 16] = v;
                }
            }
        }
    }
}

// ---------------- fallback GEMM (fp32 staging — proven) ----------------
template <bool ADD>
__global__ __launch_bounds__(256) void moe_mfma_kernel(
    const float* __restrict__ x,
    const float* __restrict__ ew,
    const float* __restrict__ eb,
    const int* __restrict__ counts,
    const int2* __restrict__ entries,
    float* __restrict__ out)
{
    const int flat = blockIdx.x;
    const int lid  = (flat & 7) * 128 + (flat >> 3);
    const int h0 = (lid & 7) * 128;
    const int i0 = ((lid >> 3) & 7) * 128;
    const int e  = lid >> 6;

    int count = counts[e];
    if (count > CAP) count = CAP;
    if (i0 >= count) return;

    __shared__ unsigned short Xs[2][128][KPAD];
    __shared__ unsigned short Ws[2][128][KPAD];
    __shared__ int   s_tok[128];
    __shared__ float s_w[128];

    const int tid = threadIdx.x;
    if (tid < 128) {
        const int i = i0 + tid;
        if (i < count) {
            int2 en = entries[e * CAP + i];
            s_tok[tid] = en.x;
            s_w[tid] = __int_as_float(en.y);
        } else {
            s_tok[tid] = 0;
            s_w[tid] = 0.0f;
        }
    }
    __syncthreads();

    const int wave = tid >> 6;
    const int lane = tid & 63;
    const int wr = (wave >> 1) * 64;
    const int wc = (wave & 1) * 64;
    const int l15 = lane & 15;
    const int quad = lane >> 4;

    f32x4 acc[4][4] = {};

    const int a_kq = (tid & 7) * 4;
    const int a_r0 = tid >> 3;
    const int b_n  = tid & 127;
    const int b_dh = (tid >> 7) * 16;

    const float* ap[4];
#pragma unroll
    for (int it = 0; it < 4; ++it)
        ap[it] = x + (size_t)s_tok[a_r0 + it * 32] * D_DIM + a_kq;
    const float* bp = ew + (size_t)e * D_DIM * H_DIM
                    + (size_t)b_dh * H_DIM + h0 + b_n;

    float4 pa[4];
    float  pb[16];
#pragma unroll
    for (int it = 0; it < 4; ++it) pa[it] = *(const float4*)(ap[it]);
#pragma unroll
    for (int i = 0; i < 16; ++i)  pb[i] = bp[(size_t)i * H_DIM];

    {
#pragma unroll
        for (int it = 0; it < 4; ++it) {
            ushort4 p;
            p.x = f2bf(pa[it].x); p.y = f2bf(pa[it].y);
            p.z = f2bf(pa[it].z); p.w = f2bf(pa[it].w);
            *(ushort4*)&Xs[0][a_r0 + it * 32][a_kq] = p;
        }
        uint4 lo, hi;
        lo.x = pk2bf(pb[0], pb[1]);   lo.y = pk2bf(pb[2], pb[3]);
        lo.z = pk2bf(pb[4], pb[5]);   lo.w = pk2bf(pb[6], pb[7]);
        hi.x = pk2bf(pb[8], pb[9]);   hi.y = pk2bf(pb[10], pb[11]);
        hi.z = pk2bf(pb[12], pb[13]); hi.w = pk2bf(pb[14], pb[15]);
        *(uint4*)&Ws[0][b_n][b_dh]     = lo;
        *(uint4*)&Ws[0][b_n][b_dh + 8] = hi;
    }

    int cur = 0;
    for (int d0 = 0; d0 < D_DIM; d0 += 32) {
        __syncthreads();
        const bool more = (d0 + 32 < D_DIM);

        if (more) {
#pragma unroll
            for (int it = 0; it < 4; ++it)
                pa[it] = *(const float4*)(ap[it] + d0 + 32);
#pragma unroll
            for (int i = 0; i < 16; ++i)
                pb[i] = bp[(size_t)(d0 + 32 + i) * H_DIM];
        }

        bf16x8 af[4], bq[4];
#pragma unroll
        for (int i = 0; i < 4; ++i)
            af[i] = *(const bf16x8*)&Xs[cur][wr + i * 16 + l15][quad * 8];
#pragma unroll
        for (int j = 0; j < 4; ++j)
            bq[j] = *(const bf16x8*)&Ws[cur][wc + j * 16 + l15][quad * 8];
#pragma unroll
        for (int i = 0; i < 4; ++i)
#pragma unroll
            for (int j = 0; j < 4; ++j)
                acc[i][j] = __builtin_amdgcn_mfma_f32_16x16x32_bf16(
                    af[i], bq[j], acc[i][j], 0, 0, 0);

        if (more) {
            const int nxt = cur ^ 1;
#pragma unroll
            for (int it = 0; it < 4; ++it) {
                ushort4 p;
                p.x = f2bf(pa[it].x); p.y = f2bf(pa[it].y);
                p.z = f2bf(pa[it].z); p.w = f2bf(pa[it].w);
                *(ushort4*)&Xs[nxt][a_r0 + it * 32][a_kq] = p;
            }
            uint4 lo, hi;
            lo.x = pk2bf(pb[0], pb[1]);   lo.y = pk2bf(pb[2], pb[3]);
            lo.z = pk2bf(pb[4], pb[5]);   lo.w = pk2bf(pb[6], pb[7]);
            hi.x = pk2bf(pb[8], pb[9]);   hi.y = pk2bf(pb[10], pb[11]);
            hi.z = pk2bf(pb[12], pb[13]); hi.w = pk2bf(pb[14], pb[15]);
            *(uint4*)&Ws[nxt][b_n][b_dh]     = lo;
            *(uint4*)&Ws[nxt][b_n][b_dh + 8] = hi;
        }
        cur ^= 1;
    }

    float bias_j[4];
    const float* ebp = eb + e * H_DIM + h0 + wc;
#pragma unroll
    for (int j = 0; j < 4; ++j) bias_j[j] = ebp[j * 16 + l15];

#pragma unroll
    for (int i = 0; i < 4; ++i) {
#pragma unroll
        for (int r2 = 0; r2 < 4; ++r2) {
            const int orow = wr + i * 16 + quad * 4 + r2;
            if (i0 + orow < count) {
                const int tok = s_tok[orow];
                const float w = s_w[orow];
                float* op = out + (size_t)tok * H_DIM + h0 + wc + l15;
#pragma unroll
                for (int j = 0; j < 4; ++j) {
                    float v = w * (acc[i][j][r2] + bias_j[j]);
                    if (ADD) v += op[j * 16];
                    op[j * 16] = v;
                }
            }
        }
    }
}

extern "C" void kernel_launch(void* const* d_in, const int* in_sizes, int n_in,
                              void* d_out, int out_size, void* d_ws, size_t ws_size,
                              hipStream_t stream)
{
    const float* x  = (const float*)d_in[0];
    const float* rw = (const float*)d_in[1];
    const float* rb = (const float*)d_in[2];
    const float* ew = (const float*)d_in[3];
    const float* eb = (const float*)d_in[4];

    char* ws = (char*)d_ws;
    int*  counts0  = (int*)ws;
    int*  counts1  = (int*)(ws + 64);
    int2* entries0 = (int2*)(ws + 1024);
    int2* entries1 = (int2*)(ws + 1024 + E_NUM * CAP * 8);

    // bf16 precache region (guarded by ws_size)
    const size_t XB_OFF = (size_t)1 << 20;                       // 1 MB
    const size_t XB_SZ  = (size_t)N_TOK * D_DIM * 2;             // 16 MB
    const size_t WT_OFF = XB_OFF + XB_SZ;
    const size_t WT_SZ  = (size_t)E_NUM * D_DIM * H_DIM * 2;     // 32 MB
    const bool precache = ws_size >= WT_OFF + WT_SZ;

    // res[] staged in d_out (128 KB of the 32 MB output buffer). Stream
    // order: router writes res -> build_lists consumes -> pass A overwrites
    // every token row.
    int4* res = (int4*)d_out;

    if (precache) {
        unsigned short* xbp = (unsigned short*)(ws + XB_OFF);
        unsigned short* wtp = (unsigned short*)(ws + WT_OFF);
        router_kernel<true><<<N_TOK / 8, 256, 0, stream>>>(x, rw, rb, res, xbp);
        build_lists<<<E_NUM, 256, 0, stream>>>(res, counts0, counts1,
                                               entries0, entries1);
        cvt_w_kernel<<<4096, 256, 0, stream>>>(ew, wtp);
        moe_gemm_bf16<false><<<1024, 256, 0, stream>>>(
            xbp, wtp, eb, counts0, entries0, (float*)d_out);
        moe_gemm_bf16<true><<<1024, 256, 0, stream>>>(
            xbp, wtp, eb, counts1, entries1, (float*)d_out);
    } else {
        router_kernel<false><<<N_TOK / 8, 256, 0, stream>>>(x, rw, rb, res, nullptr);
        build_lists<<<E_NUM, 256, 0, stream>>>(res, counts0, counts1,
                                               entries0, entries1);
        moe_mfma_kernel<false><<<1024, 256, 0, stream>>>(
            x, ew, eb, counts0, entries0, (float*)d_out);
        moe_mfma_kernel<true><<<1024, 256, 0, stream>>>(
            x, ew, eb, counts1, entries1, (float*)d_out);
    }
}

// Round 11
// 270.268 us; speedup vs baseline: 1.5517x; 1.0241x over previous
//
#include <hip/hip_runtime.h>
#include <hip/hip_bf16.h>

// MoE block: N=8192, D=1024, H=1024, E=16, top-k=2. Inputs fp32, output fp32.
// out[n] = w1*(x@W_e1 + b_e1) + w2*(x@W_e2 + b_e2), w = top-2 of softmax.
//
// Round-16: standalone LDS-staged router (R13's fix, minus the fusion that
// killed the container 2-for-2). All other kernels byte-identical to the
// passing R15 build. This round is also the fault-isolation experiment:
// pass -> the union/branched-grid fusion was the fault; fail -> router-LDS
// itself is implicated and gets abandoned.
//   * router_lds: phase 0 = coalesced lane-distinct x reads (128B/lane),
//     bf16 xb side-product, fp32 LDS stage [8][4][260] (stripe pitch 260:
//     ds-broadcast banks {0,4,8,12}, 16B-aligned). phase 1 = same (ds,e)
//     FMA chain as the proven router, fed from LDS (identical math ->
//     identical routing decisions).
//   * build_lists / cvt_w_kernel / moe_gemm_bf16 (XCD-swizzled): unchanged.
//   * ws guard: <49MB falls back to proven fp32-staging path.
//   pass A (ADD=0): slot-0 lists -> out = w*(x@W+b)   (covers every token)
//   pass B (ADD=1): slot-1 lists -> out += w*(x@W+b)  (fp32 RMW, race-free)

#define N_TOK 8192
#define D_DIM 1024
#define H_DIM 1024
#define E_NUM 16
#define CAP   1024
#define KPAD  40    // LDS row stride in ushorts (80 B = 16B*5: b128-aligned)

typedef __attribute__((ext_vector_type(4))) float f32x4;
typedef __attribute__((ext_vector_type(8))) short bf16x8;

__device__ __forceinline__ unsigned short f2bf(float f) {
    unsigned int u = __float_as_uint(f);
    unsigned int r = u + 0x7fffu + ((u >> 16) & 1u);   // RNE
    return (unsigned short)(r >> 16);
}
__device__ __forceinline__ unsigned int pk2bf(float lo, float hi) {
    return (unsigned int)f2bf(lo) | ((unsigned int)f2bf(hi) << 16);
}

// ---------------- router, LDS-staged x (+ bf16 X side-product) ----------------
__global__ __launch_bounds__(256) void router_lds(
    const float* __restrict__ x,
    const float* __restrict__ rw,
    const float* __restrict__ rb,
    int4* __restrict__ res,
    unsigned short* __restrict__ xb)
{
    __shared__ __align__(16) float xls[8][4][260];   // [row][stripe][pos]
    __shared__ double lg[4][2][E_NUM];

    const int tid = threadIdx.x;
    const int t0b = blockIdx.x * 8;

    // ---- phase 0: coalesced x read -> bf16 xb write + fp32 LDS stage
    {
        const int r   = tid >> 5;                 // 0..7  (block-local row)
        const int c32 = (tid & 31) * 32;          // 32 floats per thread
        const int s   = c32 >> 8;                 // stripe (constant per thread)
        const int p0  = c32 & 255;
        const float* src = x + (size_t)(t0b + r) * D_DIM + c32;
        float4 v[8];
#pragma unroll
        for (int j = 0; j < 8; ++j) v[j] = *(const float4*)(src + j * 4);
#pragma unroll
        for (int j = 0; j < 8; ++j)
            *(float4*)&xls[r][s][p0 + j * 4] = v[j];
        unsigned int q[16];
#pragma unroll
        for (int j = 0; j < 8; ++j) {
            q[2 * j]     = pk2bf(v[j].x, v[j].y);
            q[2 * j + 1] = pk2bf(v[j].z, v[j].w);
        }
        unsigned short* dst = xb + (size_t)(t0b + r) * D_DIM + c32;
        *(uint4*)(dst)      = *(uint4*)&q[0];
        *(uint4*)(dst + 8)  = *(uint4*)&q[4];
        *(uint4*)(dst + 16) = *(uint4*)&q[8];
        *(uint4*)(dst + 24) = *(uint4*)&q[12];
    }
    __syncthreads();

    // ---- phase 1: (ds,e) FMA chain, x from LDS (identical math to proven)
    const int wave = tid >> 6;
    const int lane = tid & 63;
    const int ds   = lane >> 4;
    const int e    = lane & 15;
    const int lr0  = wave * 2;                    // block-local token rows
    const float* rwp = rw + ds * 4096 + e;

    double acc0 = 0.0, acc1 = 0.0;
#pragma unroll 2
    for (int g = 0; g < 8; ++g) {
        float s0 = 0.0f, s1 = 0.0f;
#pragma unroll
        for (int u = 0; u < 8; ++u) {
            const int jb = g * 8 + u;
            const float4 a = *(const float4*)&xls[lr0][ds][jb * 4];
            const float4 b = *(const float4*)&xls[lr0 + 1][ds][jb * 4];
            const float w0 = rwp[jb * 64];
            const float w1 = rwp[jb * 64 + 16];
            const float w2 = rwp[jb * 64 + 32];
            const float w3 = rwp[jb * 64 + 48];
            s0 = fmaf(a.w, w3, fmaf(a.z, w2, fmaf(a.y, w1, fmaf(a.x, w0, s0))));
            s1 = fmaf(b.w, w3, fmaf(b.z, w2, fmaf(b.y, w1, fmaf(b.x, w0, s1))));
        }
        acc0 += (double)s0;
        acc1 += (double)s1;
    }

    double v0 = acc0, v1 = acc1;
    v0 += __shfl_xor(v0, 16); v0 += __shfl_xor(v0, 32);
    v1 += __shfl_xor(v1, 16); v1 += __shfl_xor(v1, 32);

    if (ds == 0) {
        const double bias = (double)rb[e];
        lg[wave][0][e] = v0 + bias;
        lg[wave][1][e] = v1 + bias;
    }
    __syncthreads();

    if (lane < 2) {
        const double* L = lg[wave][lane];
        double m = L[0];
#pragma unroll
        for (int k = 1; k < E_NUM; ++k) m = fmax(m, L[k]);

        int e1 = 0;
#pragma unroll
        for (int k = 1; k < E_NUM; ++k) if (L[k] > L[e1]) e1 = k;
        int e2 = (e1 == 0) ? 1 : 0;
        for (int k = 0; k < E_NUM; ++k)
            if (k != e1 && L[k] > L[e2]) e2 = k;

        float s = 0.0f;
#pragma unroll
        for (int k = 0; k < E_NUM; ++k) s = fmaf(expf((float)(L[k] - m)), 1.0f, s);
        const float w1 = expf((float)(L[e1] - m)) / s;
        const float w2 = expf((float)(L[e2] - m)) / s;

        const int n = t0b + wave * 2 + lane;
        res[n] = make_int4(e1, e2, __float_as_int(w1), __float_as_int(w2));
    }
}

// ---------------- fallback router (global-broadcast x, proven) ----------------
template <bool WRITE_XB>
__global__ __launch_bounds__(256, 4) void router_kernel(
    const float* __restrict__ x,
    const float* __restrict__ rw,
    const float* __restrict__ rb,
    int4* __restrict__ res,
    unsigned short* __restrict__ xb)
{
    const int wave = threadIdx.x >> 6;
    const int lane = threadIdx.x & 63;
    const int ds   = lane >> 4;
    const int e    = lane & 15;
    const int t0   = blockIdx.x * 8 + wave * 2;

    const float* x0  = x + (size_t)t0 * D_DIM + ds * 256;
    const float* x1  = x0 + D_DIM;
    const float* rwp = rw + ds * 4096 + e;

    double acc0 = 0.0, acc1 = 0.0;
#pragma unroll 2
    for (int g = 0; g < 8; ++g) {
        float s0 = 0.0f, s1 = 0.0f;
#pragma unroll
        for (int u = 0; u < 8; ++u) {
            const int jb = g * 8 + u;
            const float4 a = *(const float4*)(x0 + jb * 4);
            const float4 b = *(const float4*)(x1 + jb * 4);
            const float w0 = rwp[jb * 64];
            const float w1 = rwp[jb * 64 + 16];
            const float w2 = rwp[jb * 64 + 32];
            const float w3 = rwp[jb * 64 + 48];
            s0 = fmaf(a.w, w3, fmaf(a.z, w2, fmaf(a.y, w1, fmaf(a.x, w0, s0))));
            s1 = fmaf(b.w, w3, fmaf(b.z, w2, fmaf(b.y, w1, fmaf(b.x, w0, s1))));
        }
        acc0 += (double)s0;
        acc1 += (double)s1;
    }

    if (WRITE_XB) {
#pragma unroll
        for (int t = 0; t < 2; ++t) {
            const float* src = x + (size_t)(t0 + t) * D_DIM + lane * 16;
            unsigned short* dst = xb + (size_t)(t0 + t) * D_DIM + lane * 16;
            const float4 v0 = *(const float4*)(src);
            const float4 v1 = *(const float4*)(src + 4);
            const float4 v2 = *(const float4*)(src + 8);
            const float4 v3 = *(const float4*)(src + 12);
            uint4 lo, hi;
            lo.x = pk2bf(v0.x, v0.y); lo.y = pk2bf(v0.z, v0.w);
            lo.z = pk2bf(v1.x, v1.y); lo.w = pk2bf(v1.z, v1.w);
            hi.x = pk2bf(v2.x, v2.y); hi.y = pk2bf(v2.z, v2.w);
            hi.z = pk2bf(v3.x, v3.y); hi.w = pk2bf(v3.z, v3.w);
            *(uint4*)dst       = lo;
            *(uint4*)(dst + 8) = hi;
        }
    }

    double v0 = acc0, v1 = acc1;
    v0 += __shfl_xor(v0, 16); v0 += __shfl_xor(v0, 32);
    v1 += __shfl_xor(v1, 16); v1 += __shfl_xor(v1, 32);

    __shared__ double lg[4][2][E_NUM];
    if (ds == 0) {
        const double bias = (double)rb[e];
        lg[wave][0][e] = v0 + bias;
        lg[wave][1][e] = v1 + bias;
    }
    __syncthreads();

    if (lane < 2) {
        const double* L = lg[wave][lane];
        double m = L[0];
#pragma unroll
        for (int k = 1; k < E_NUM; ++k) m = fmax(m, L[k]);

        int e1 = 0;
#pragma unroll
        for (int k = 1; k < E_NUM; ++k) if (L[k] > L[e1]) e1 = k;
        int e2 = (e1 == 0) ? 1 : 0;
        for (int k = 0; k < E_NUM; ++k)
            if (k != e1 && L[k] > L[e2]) e2 = k;

        float s = 0.0f;
#pragma unroll
        for (int k = 0; k < E_NUM; ++k) s = fmaf(expf((float)(L[k] - m)), 1.0f, s);
        const float w1 = expf((float)(L[e1] - m)) / s;
        const float w2 = expf((float)(L[e2] - m)) / s;

        const int n = t0 + lane;
        res[n] = make_int4(e1, e2, __float_as_int(w1), __float_as_int(w2));
    }
}

// ---------------- build_lists (unchanged) ----------------
__global__ __launch_bounds__(256) void build_lists(
    const int4* __restrict__ res,
    int* __restrict__ counts0, int* __restrict__ counts1,
    int2* __restrict__ entries0, int2* __restrict__ entries1)
{
    const int e = blockIdx.x;
    __shared__ int c0, c1;
    if (threadIdx.x == 0) { c0 = 0; c1 = 0; }
    __syncthreads();

    for (int i = threadIdx.x; i < N_TOK; i += 256) {
        const int4 r = res[i];
        if (r.x == e) {
            int p = atomicAdd(&c0, 1);
            if (p < CAP) entries0[e * CAP + p] = make_int2(i, r.z);
        }
        if (r.y == e) {
            int p = atomicAdd(&c1, 1);
            if (p < CAP) entries1[e * CAP + p] = make_int2(i, r.w);
        }
    }
    __syncthreads();
    if (threadIdx.x == 0) { counts0[e] = c0; counts1[e] = c1; }
}

// ---------------- cvt: Wt = bf16(W) transposed [E][H][D] ----------------
__global__ __launch_bounds__(256) void cvt_w_kernel(
    const float* __restrict__ ew,
    unsigned short* __restrict__ wt)
{
    const int tid = threadIdx.x;
    __shared__ unsigned short Ts[64][68];
    const int wi = blockIdx.x;                // 0..4095
    const int e  = wi >> 8;                   // 256 tiles/expert
    const int kt = (wi >> 4) & 15;
    const int ht = wi & 15;

    // read: 64 k-rows x 64 h, coalesced float4, convert, store [k][h]
    {
        const int kl0 = tid >> 4;             // 0..15 (+16*i)
        const int hl  = (tid & 15) * 4;
        const float* src = ew + (size_t)e * (D_DIM * H_DIM)
                         + (size_t)(kt * 64 + kl0) * H_DIM + ht * 64 + hl;
#pragma unroll
        for (int i = 0; i < 4; ++i) {
            const float4 v = *(const float4*)(src + (size_t)i * 16 * H_DIM);
            ushort4 p;
            p.x = f2bf(v.x); p.y = f2bf(v.y); p.z = f2bf(v.z); p.w = f2bf(v.w);
            *(ushort4*)&Ts[kl0 + i * 16][hl] = p;
        }
    }
    __syncthreads();
    // write: 64 h-rows x 64 k, transposed gather from LDS, 32B/thread
    {
        const int h2 = tid >> 2;              // 0..63
        const int kc = (tid & 3) * 16;
        unsigned int r[8];
#pragma unroll
        for (int i = 0; i < 8; ++i)
            r[i] = (unsigned int)Ts[kc + 2 * i][h2]
                 | ((unsigned int)Ts[kc + 2 * i + 1][h2] << 16);
        unsigned short* dst = wt + (size_t)e * (D_DIM * H_DIM)
                            + (size_t)(ht * 64 + h2) * D_DIM + kt * 64 + kc;
        *(uint4*)dst       = *(uint4*)&r[0];
        *(uint4*)(dst + 8) = *(uint4*)&r[4];
    }
}

// ---------------- GEMM: bf16 precache, dense worklist + XCD swizzle ----------------
template <bool ADD>
__global__ __launch_bounds__(256) void moe_gemm_bf16(
    const unsigned short* __restrict__ xb,   // [N][D] bf16
    const unsigned short* __restrict__ wt,   // [E][H][D] bf16
    const float* __restrict__ eb,
    const int* __restrict__ counts,
    const int2* __restrict__ entries,
    float* __restrict__ out)
{
    // total active blocks T (uniform across blocks, from counts)
    int T = 0;
    for (int k = 0; k < E_NUM; ++k) {
        int c = counts[k]; if (c > CAP) c = CAP;
        T += ((c + 127) >> 7) << 3;            // ceil(c/128) * 8 h-blocks
    }
    if ((int)blockIdx.x >= T) return;

    // m204 bijective XCD swizzle over [0,T): b=8k+xcd -> contiguous loc
    // chunk per XCD, so the 8 h-blocks sharing an X tile stay on one XCD.
    const int q = T >> 3, r = T & 7;
    const int xcd = blockIdx.x & 7;
    int loc = (xcd < r ? xcd * (q + 1) : r * (q + 1) + (xcd - r) * q)
            + (blockIdx.x >> 3);

    // walk: loc -> (e, i-chunk, h)
    int e = 0, count = 0;
    for (; e < E_NUM; ++e) {
        int c = counts[e]; if (c > CAP) c = CAP;
        const int nb = ((c + 127) >> 7) << 3;
        if (loc < nb) { count = c; break; }
        loc -= nb;
    }
    const int i0 = (loc >> 3) * 128;
    const int h0 = (loc & 7) * 128;

    __shared__ unsigned short Xs[2][128][KPAD];
    __shared__ unsigned short Ws[2][128][KPAD];
    __shared__ int   s_tok[128];
    __shared__ float s_w[128];

    const int tid = threadIdx.x;
    if (tid < 128) {
        const int i = i0 + tid;
        if (i < count) {
            int2 en = entries[e * CAP + i];
            s_tok[tid] = en.x;
            s_w[tid] = __int_as_float(en.y);
        } else {
            s_tok[tid] = 0;
            s_w[tid] = 0.0f;
        }
    }
    __syncthreads();

    const int wave = tid >> 6;
    const int lane = tid & 63;
    const int wr = (wave >> 1) * 64;
    const int wc = (wave & 1) * 64;
    const int l15 = lane & 15;
    const int quad = lane >> 4;

    f32x4 acc[4][4] = {};

    // staging map: thread -> (row 0..127, 16-ushort half)
    const int row  = tid >> 1;
    const int half = (tid & 1) * 16;
    const unsigned short* xp = xb + (size_t)s_tok[row] * D_DIM + half;
    const unsigned short* wp = wt + (size_t)(e * H_DIM + h0 + row) * D_DIM + half;

    // prefetch tile 0 -> regs -> buf 0
    uint4 pa0 = *(const uint4*)(xp);
    uint4 pa1 = *(const uint4*)(xp + 8);
    uint4 pw0 = *(const uint4*)(wp);
    uint4 pw1 = *(const uint4*)(wp + 8);
    *(uint4*)&Xs[0][row][half]     = pa0;
    *(uint4*)&Xs[0][row][half + 8] = pa1;
    *(uint4*)&Ws[0][row][half]     = pw0;
    *(uint4*)&Ws[0][row][half + 8] = pw1;

    int cur = 0;
    for (int d0 = 0; d0 < D_DIM; d0 += 32) {
        __syncthreads();                       // buf[cur] ready
        const bool more = (d0 + 32 < D_DIM);

        if (more) {                            // issue next-tile loads
            pa0 = *(const uint4*)(xp + d0 + 32);
            pa1 = *(const uint4*)(xp + d0 + 40);
            pw0 = *(const uint4*)(wp + d0 + 32);
            pw1 = *(const uint4*)(wp + d0 + 40);
        }

        bf16x8 af[4], bq[4];
#pragma unroll
        for (int i = 0; i < 4; ++i)
            af[i] = *(const bf16x8*)&Xs[cur][wr + i * 16 + l15][quad * 8];
#pragma unroll
        for (int j = 0; j < 4; ++j)
            bq[j] = *(const bf16x8*)&Ws[cur][wc + j * 16 + l15][quad * 8];
#pragma unroll
        for (int i = 0; i < 4; ++i)
#pragma unroll
            for (int j = 0; j < 4; ++j)
                acc[i][j] = __builtin_amdgcn_mfma_f32_16x16x32_bf16(
                    af[i], bq[j], acc[i][j], 0, 0, 0);

        if (more) {                            // write next tile
            const int nxt = cur ^ 1;
            *(uint4*)&Xs[nxt][row][half]     = pa0;
            *(uint4*)&Xs[nxt][row][half + 8] = pa1;
            *(uint4*)&Ws[nxt][row][half]     = pw0;
            *(uint4*)&Ws[nxt][row][half + 8] = pw1;
        }
        cur ^= 1;
    }

    float bias_j[4];
    const float* ebp = eb + e * H_DIM + h0 + wc;
#pragma unroll
    for (int j = 0; j < 4; ++j) bias_j[j] = ebp[j * 16 + l15];

#pragma unroll
    for (int i = 0; i < 4; ++i) {
#pragma unroll
        for (int r2 = 0; r2 < 4; ++r2) {
            const int orow = wr + i * 16 + quad * 4 + r2;
            if (i0 + orow < count) {
                const int tok = s_tok[orow];
                const float w = s_w[orow];
                float* op = out + (size_t)tok * H_DIM + h0 + wc + l15;
#pragma unroll
                for (int j = 0; j < 4; ++j) {
                    float v = w * (acc[i][j][r2] + bias_j[j]);
                    if (ADD) v += op[j * 16];
                    op[j * 16] = v;
                }
            }
        }
    }
}

// ---------------- fallback GEMM (fp32 staging — proven) ----------------
template <bool ADD>
__global__ __launch_bounds__(256) void moe_mfma_kernel(
    const float* __restrict__ x,
    const float* __restrict__ ew,
    const float* __restrict__ eb,
    const int* __restrict__ counts,
    const int2* __restrict__ entries,
    float* __restrict__ out)
{
    const int flat = blockIdx.x;
    const int lid  = (flat & 7) * 128 + (flat >> 3);
    const int h0 = (lid & 7) * 128;
    const int i0 = ((lid >> 3) & 7) * 128;
    const int e  = lid >> 6;

    int count = counts[e];
    if (count > CAP) count = CAP;
    if (i0 >= count) return;

    __shared__ unsigned short Xs[2][128][KPAD];
    __shared__ unsigned short Ws[2][128][KPAD];
    __shared__ int   s_tok[128];
    __shared__ float s_w[128];

    const int tid = threadIdx.x;
    if (tid < 128) {
        const int i = i0 + tid;
        if (i < count) {
            int2 en = entries[e * CAP + i];
            s_tok[tid] = en.x;
            s_w[tid] = __int_as_float(en.y);
        } else {
            s_tok[tid] = 0;
            s_w[tid] = 0.0f;
        }
    }
    __syncthreads();

    const int wave = tid >> 6;
    const int lane = tid & 63;
    const int wr = (wave >> 1) * 64;
    const int wc = (wave & 1) * 64;
    const int l15 = lane & 15;
    const int quad = lane >> 4;

    f32x4 acc[4][4] = {};

    const int a_kq = (tid & 7) * 4;
    const int a_r0 = tid >> 3;
    const int b_n  = tid & 127;
    const int b_dh = (tid >> 7) * 16;

    const float* ap[4];
#pragma unroll
    for (int it = 0; it < 4; ++it)
        ap[it] = x + (size_t)s_tok[a_r0 + it * 32] * D_DIM + a_kq;
    const float* bp = ew + (size_t)e * D_DIM * H_DIM
                    + (size_t)b_dh * H_DIM + h0 + b_n;

    float4 pa[4];
    float  pb[16];
#pragma unroll
    for (int it = 0; it < 4; ++it) pa[it] = *(const float4*)(ap[it]);
#pragma unroll
    for (int i = 0; i < 16; ++i)  pb[i] = bp[(size_t)i * H_DIM];

    {
#pragma unroll
        for (int it = 0; it < 4; ++it) {
            ushort4 p;
            p.x = f2bf(pa[it].x); p.y = f2bf(pa[it].y);
            p.z = f2bf(pa[it].z); p.w = f2bf(pa[it].w);
            *(ushort4*)&Xs[0][a_r0 + it * 32][a_kq] = p;
        }
        uint4 lo, hi;
        lo.x = pk2bf(pb[0], pb[1]);   lo.y = pk2bf(pb[2], pb[3]);
        lo.z = pk2bf(pb[4], pb[5]);   lo.w = pk2bf(pb[6], pb[7]);
        hi.x = pk2bf(pb[8], pb[9]);   hi.y = pk2bf(pb[10], pb[11]);
        hi.z = pk2bf(pb[12], pb[13]); hi.w = pk2bf(pb[14], pb[15]);
        *(uint4*)&Ws[0][b_n][b_dh]     = lo;
        *(uint4*)&Ws[0][b_n][b_dh + 8] = hi;
    }

    int cur = 0;
    for (int d0 = 0; d0 < D_DIM; d0 += 32) {
        __syncthreads();
        const bool more = (d0 + 32 < D_DIM);

        if (more) {
#pragma unroll
            for (int it = 0; it < 4; ++it)
                pa[it] = *(const float4*)(ap[it] + d0 + 32);
#pragma unroll
            for (int i = 0; i < 16; ++i)
                pb[i] = bp[(size_t)(d0 + 32 + i) * H_DIM];
        }

        bf16x8 af[4], bq[4];
#pragma unroll
        for (int i = 0; i < 4; ++i)
            af[i] = *(const bf16x8*)&Xs[cur][wr + i * 16 + l15][quad * 8];
#pragma unroll
        for (int j = 0; j < 4; ++j)
            bq[j] = *(const bf16x8*)&Ws[cur][wc + j * 16 + l15][quad * 8];
#pragma unroll
        for (int i = 0; i < 4; ++i)
#pragma unroll
            for (int j = 0; j < 4; ++j)
                acc[i][j] = __builtin_amdgcn_mfma_f32_16x16x32_bf16(
                    af[i], bq[j], acc[i][j], 0, 0, 0);

        if (more) {
            const int nxt = cur ^ 1;
#pragma unroll
            for (int it = 0; it < 4; ++it) {
                ushort4 p;
                p.x = f2bf(pa[it].x); p.y = f2bf(pa[it].y);
                p.z = f2bf(pa[it].z); p.w = f2bf(pa[it].w);
                *(ushort4*)&Xs[nxt][a_r0 + it * 32][a_kq] = p;
            }
            uint4 lo, hi;
            lo.x = pk2bf(pb[0], pb[1]);   lo.y = pk2bf(pb[2], pb[3]);
            lo.z = pk2bf(pb[4], pb[5]);   lo.w = pk2bf(pb[6], pb[7]);
            hi.x = pk2bf(pb[8], pb[9]);   hi.y = pk2bf(pb[10], pb[11]);
            hi.z = pk2bf(pb[12], pb[13]); hi.w = pk2bf(pb[14], pb[15]);
            *(uint4*)&Ws[nxt][b_n][b_dh]     = lo;
            *(uint4*)&Ws[nxt][b_n][b_dh + 8] = hi;
        }
        cur ^= 1;
    }

    float bias_j[4];
    const float* ebp = eb + e * H_DIM + h0 + wc;
#pragma unroll
    for (int j = 0; j < 4; ++j) bias_j[j] = ebp[j * 16 + l15];

#pragma unroll
    for (int i = 0; i < 4; ++i) {
#pragma unroll
        for (int r2 = 0; r2 < 4; ++r2) {
            const int orow = wr + i * 16 + quad * 4 + r2;
            if (i0 + orow < count) {
                const int tok = s_tok[orow];
                const float w = s_w[orow];
                float* op = out + (size_t)tok * H_DIM + h0 + wc + l15;
#pragma unroll
                for (int j = 0; j < 4; ++j) {
                    float v = w * (acc[i][j][r2] + bias_j[j]);
                    if (ADD) v += op[j * 16];
                    op[j * 16] = v;
                }
            }
        }
    }
}

extern "C" void kernel_launch(void* const* d_in, const int* in_sizes, int n_in,
                              void* d_out, int out_size, void* d_ws, size_t ws_size,
                              hipStream_t stream)
{
    const float* x  = (const float*)d_in[0];
    const float* rw = (const float*)d_in[1];
    const float* rb = (const float*)d_in[2];
    const float* ew = (const float*)d_in[3];
    const float* eb = (const float*)d_in[4];

    char* ws = (char*)d_ws;
    int*  counts0  = (int*)ws;
    int*  counts1  = (int*)(ws + 64);
    int2* entries0 = (int2*)(ws + 1024);
    int2* entries1 = (int2*)(ws + 1024 + E_NUM * CAP * 8);

    // bf16 precache region (guarded by ws_size)
    const size_t XB_OFF = (size_t)1 << 20;                       // 1 MB
    const size_t XB_SZ  = (size_t)N_TOK * D_DIM * 2;             // 16 MB
    const size_t WT_OFF = XB_OFF + XB_SZ;
    const size_t WT_SZ  = (size_t)E_NUM * D_DIM * H_DIM * 2;     // 32 MB
    const bool precache = ws_size >= WT_OFF + WT_SZ;

    // res[] staged in d_out (128 KB of the 32 MB output buffer). Stream
    // order: router writes res -> build_lists consumes -> pass A overwrites
    // every token row.
    int4* res = (int4*)d_out;

    if (precache) {
        unsigned short* xbp = (unsigned short*)(ws + XB_OFF);
        unsigned short* wtp = (unsigned short*)(ws + WT_OFF);
        router_lds<<<N_TOK / 8, 256, 0, stream>>>(x, rw, rb, res, xbp);
        build_lists<<<E_NUM, 256, 0, stream>>>(res, counts0, counts1,
                                               entries0, entries1);
        cvt_w_kernel<<<4096, 256, 0, stream>>>(ew, wtp);
        moe_gemm_bf16<false><<<1024, 256, 0, stream>>>(
            xbp, wtp, eb, counts0, entries0, (float*)d_out);
        moe_gemm_bf16<true><<<1024, 256, 0, stream>>>(
            xbp, wtp, eb, counts1, entries1, (float*)d_out);
    } else {
        router_kernel<false><<<N_TOK / 8, 256, 0, stream>>>(x, rw, rb, res, nullptr);
        build_lists<<<E_NUM, 256, 0, stream>>>(res, counts0, counts1,
                                               entries0, entries1);
        moe_mfma_kernel<false><<<1024, 256, 0, stream>>>(
            x, ew, eb, counts0, entries0, (float*)d_out);
        moe_mfma_kernel<true><<<1024, 256, 0, stream>>>(
            x, ew, eb, counts1, entries1, (float*)d_out);
    }
}